// Round 8
// baseline (5038.172 us; speedup 1.0000x reference)
//
#include <hip/hip_runtime.h>
#include <math.h>

#define NE 320000
#define NNODES 10000
#define EB 32
#define NBLK (NE / EB)
#define AST 360   // Ah stride (f16 elems)
#define BST 264   // AhB stride (f16 elems)

typedef _Float16 f16x8 __attribute__((ext_vector_type(8)));
typedef float f32x4 __attribute__((ext_vector_type(4)));

__device__ __forceinline__ float silu(float x) { return x / (1.0f + __expf(-x)); }
__device__ __forceinline__ float cutf(float len) {
    float x = len * (1.0f / 6.0f);
    float x2 = x * x, x6 = x2 * x2 * x2;
    float f = 1.0f - 28.0f * x6 + 48.0f * x6 * x - 21.0f * x6 * x2;
    return (x < 1.0f) ? f : 0.0f;
}

// ---------------------------------------------------------------- zero
__global__ __launch_bounds__(256) void k_zero(float* __restrict__ p, int n) {
    int i = blockIdx.x * 256 + threadIdx.x;
    if (i < n) p[i] = 0.f;
}

// ---------------------------------------------------------------- fragment-major pack for MLP weights
__global__ __launch_bounds__(256) void k_packf(const float* __restrict__ src,
                                               _Float16* __restrict__ dst,
                                               int K, int KS, int NT, int stride,
                                               int colOff) {
    int i = blockIdx.x * 256 + threadIdx.x;
    if (i >= NT * KS * 512) return;
    int j = i & 7, lane = (i >> 3) & 63;
    int blk = i >> 9;
    int ks = blk % KS, nt = blk / KS;
    int k = ks * 32 + (lane >> 4) * 8 + j;
    int n = colOff + nt * 16 + (lane & 15);
    dst[i] = (k < K) ? (_Float16)src[(size_t)k * stride + n] : (_Float16)0.f;
}

// ---------------------------------------------------------------- fragment-major pack of Wfinlat (contraction B)
__global__ __launch_bounds__(256) void k_packfin(const float* __restrict__ W,
                                                 _Float16* __restrict__ dst) {
    int i = blockIdx.x * 256 + threadIdx.x;  // < 786432
    int j = i & 7, lane = (i >> 3) & 63, cc = (i >> 9) & 7, ke = (i >> 12) & 31,
        combo = i >> 17;
    int n = (combo >> 1) * 1024 + ke * 32 + (combo & 1) * 16 + (lane & 15);
    int c = cc * 32 + (lane >> 4) * 8 + j;
    dst[i] = (_Float16)W[(size_t)c * 3072 + n];
}

// ---------------------------------------------------------------- MFMA GEMM, 32 edges (2 m-tiles), frag-major B
template <int NT>
__device__ __forceinline__ void mfma_gemm2(int ksteps, const _Float16* Ah, int astride,
                                           const _Float16* __restrict__ Wt, int t,
                                           f32x4* acc0, f32x4* acc1) {
    int wave = t >> 6, lane = t & 63, r = lane & 15, g = lane >> 4;
    const int TPW = (NT + 3) / 4;
#pragma unroll
    for (int i = 0; i < TPW; ++i) {
        acc0[i] = (f32x4){0.f, 0.f, 0.f, 0.f};
        acc1[i] = (f32x4){0.f, 0.f, 0.f, 0.f};
    }
    for (int ks = 0; ks < ksteps; ++ks) {
        f16x8 a0 = *(const f16x8*)(Ah + r * astride + ks * 32 + g * 8);
        f16x8 a1 = *(const f16x8*)(Ah + (16 + r) * astride + ks * 32 + g * 8);
#pragma unroll
        for (int i = 0; i < TPW; ++i) {
            int nt = wave + 4 * i;
            if (nt < NT) {
                f16x8 b = *(const f16x8*)(Wt + ((size_t)(nt * ksteps + ks) * 64 + lane) * 8);
                acc0[i] = __builtin_amdgcn_mfma_f32_16x16x32_f16(a0, b, acc0[i], 0, 0, 0);
                acc1[i] = __builtin_amdgcn_mfma_f32_16x16x32_f16(a1, b, acc1[i], 0, 0, 0);
            }
        }
    }
}

// gather lat_in -> Ah cols 0..159 (f16), compute s_cut
__device__ __forceinline__ void gather_latin(
    const float* __restrict__ nodeinv, const float* __restrict__ edgeinv,
    const float* __restrict__ elen, const int* __restrict__ eidx,
    int e0, int t, _Float16* Ah, float* s_cut) {
    if (t < EB) s_cut[t] = cutf(elen[e0 + t]);
    for (int i = t; i < EB * 160; i += 256) {
        int ee = i / 160, k = i - ee * 160;
        int e = e0 + ee;
        float v;
        if (k < 64)       v = nodeinv[eidx[e] * 64 + k];
        else if (k < 128) v = nodeinv[eidx[NE + e] * 64 + (k - 64)];
        else if (k < 136) v = edgeinv[(size_t)e * 8 + (k - 128)];
        else              v = 0.f;
        Ah[ee * AST + k] = (_Float16)v;
    }
}

// lat0 (2 GEMMs) -> Ah cols 0..255 f16
__device__ __forceinline__ void lat0_mfma2(const _Float16* __restrict__ W2aT,
                                           const _Float16* __restrict__ W2bT,
                                           int t, _Float16* Ah, _Float16* AhB,
                                           const float* s_cut) {
    int wave = t >> 6, lane = t & 63, r = lane & 15, g = lane >> 4;
    f32x4 acc0[4], acc1[4];
    mfma_gemm2<16>(5, Ah, AST, W2aT, t, acc0, acc1);
#pragma unroll
    for (int i = 0; i < 4; ++i) {
        int nt = wave + 4 * i;
#pragma unroll
        for (int i2 = 0; i2 < 4; ++i2) {
            AhB[(g * 4 + i2) * BST + nt * 16 + r] = (_Float16)silu(acc0[i][i2]);
            AhB[(16 + g * 4 + i2) * BST + nt * 16 + r] = (_Float16)silu(acc1[i][i2]);
        }
    }
    __syncthreads();
    mfma_gemm2<16>(8, AhB, BST, W2bT, t, acc0, acc1);
#pragma unroll
    for (int i = 0; i < 4; ++i) {
        int nt = wave + 4 * i;
#pragma unroll
        for (int i2 = 0; i2 < 4; ++i2) {
            int ro = g * 4 + i2, col = nt * 16 + r;
            Ah[ro * AST + col] = (_Float16)(s_cut[ro] * silu(acc0[i][i2]));
            Ah[(16 + ro) * AST + col] = (_Float16)(s_cut[16 + ro] * silu(acc1[i][i2]));
        }
    }
    __syncthreads();
}

// lnorm(featN[center]) -> Ah cols 256..351 f16
__device__ __forceinline__ void gather_lnorm(const float* __restrict__ featN,
                                             const int* __restrict__ eidx,
                                             int e0, int t, _Float16* Ah) {
    for (int i = t; i < EB * 96; i += 256) {
        int ee = i / 96, rem = i - ee * 96;
        int l = rem >> 5, kk = rem & 31;
        int off = (l == 0) ? 0 : ((l == 1) ? 1 : 4);
        int d = (l == 0) ? 1 : ((l == 1) ? 3 : 5);
        const float* f = featN + (size_t)eidx[e0 + ee] * 288 + kk;
        float s = 1e-8f;
        for (int mm = off; mm < off + d; ++mm) { float x = f[mm * 32]; s = fmaf(x, x, s); }
        Ah[ee * AST + 256 + rem] = (_Float16)sqrtf(s);
    }
}

// scatter env += weight_channels(sh, s_w)*cut  (s_w f32 [EB][96])
__device__ __forceinline__ void scatter_env(const float* __restrict__ edge_attr,
                                            const int* __restrict__ eidx,
                                            const float* s_w, const float* s_cut,
                                            int e0, int t, float* __restrict__ env) {
    for (int i = t; i < EB * 32; i += 256) {
        int el = i >> 5, k = i & 31;
        int e = e0 + el;
        float cw = s_cut[el];
        int n = eidx[e];
        float w0 = s_w[el * 96 + k * 3 + 0] * cw;
        float w1 = s_w[el * 96 + k * 3 + 1] * cw;
        float w2 = s_w[el * 96 + k * 3 + 2] * cw;
        float* dst = env + (size_t)n * 288 + k;
#pragma unroll
        for (int m = 0; m < 9; ++m) {
            float w = (m == 0) ? w0 : ((m < 4) ? w1 : w2);
            atomicAdd(dst + m * 32, edge_attr[(size_t)e * 9 + m] * w);
        }
    }
}

// NT=6 epilogue -> s_w (f32)
__device__ __forceinline__ void epi6_f32(const f32x4* acc0, const f32x4* acc1, int t,
                                         float* s_w) {
    int wave = t >> 6, lane = t & 63, r = lane & 15, g = lane >> 4;
#pragma unroll
    for (int i = 0; i < 2; ++i) {
        int nt = wave + 4 * i;
        if (nt < 6) {
#pragma unroll
            for (int i2 = 0; i2 < 4; ++i2) {
                s_w[(g * 4 + i2) * 96 + nt * 16 + r] = acc0[i][i2];
                s_w[(16 + g * 4 + i2) * 96 + nt * 16 + r] = acc1[i][i2];
            }
        }
    }
}

// ---------------------------------------------------------------- K1: lat0 + (lat0@Wenv0b) + scatter
__global__ __launch_bounds__(256) void k1_lat_scatter0(
    const float* __restrict__ nodeinv, const float* __restrict__ edgeinv,
    const float* __restrict__ elen, const float* __restrict__ edge_attr,
    const int* __restrict__ eidx, const _Float16* __restrict__ W2aT,
    const _Float16* __restrict__ W2bT, const _Float16* __restrict__ Wenv0bT,
    float* __restrict__ env) {
    __shared__ alignas(16) _Float16 Ah[EB * AST];
    __shared__ alignas(16) _Float16 AhB[EB * BST];
    __shared__ float s_cut[EB];
    float* s_w = (float*)AhB;  // overlay: AhB dead after lat0
    int t = threadIdx.x;
    int e0 = blockIdx.x * EB;
    gather_latin(nodeinv, edgeinv, elen, eidx, e0, t, Ah, s_cut);
    __syncthreads();
    lat0_mfma2(W2aT, W2bT, t, Ah, AhB, s_cut);
    f32x4 acc0[4], acc1[4];
    mfma_gemm2<6>(8, Ah, AST, Wenv0bT, t, acc0, acc1);
    epi6_f32(acc0, acc1, t, s_w);
    __syncthreads();
    scatter_env(edge_attr, eidx, s_w, s_cut, e0, t, env);
}

// ---------------------------------------------------------------- node transform (unchanged)
__global__ __launch_bounds__(288) void k_node(
    const float* envin, const float* __restrict__ nodeinv,
    const float* __restrict__ Wenvlin, const float* __restrict__ Wprod,
    const float* __restrict__ Wfeat, float* featOut) {
    __shared__ float s_env[288];
    __shared__ float s_inv[64];
    __shared__ float s_mix[288];
    __shared__ float s_ew[96];
    int n = blockIdx.x;
    int t = threadIdx.x;
    s_env[t] = envin[(size_t)n * 288 + t] * (1.0f / 32.0f);
    if (t < 64) s_inv[t] = nodeinv[n * 64 + t];
    __syncthreads();
    int m = t >> 5, j = t & 31;
    int l = (m == 0) ? 0 : ((m < 4) ? 1 : 2);
    float a = 0.f;
    for (int k = 0; k < 32; ++k) a = fmaf(s_env[m * 32 + k], Wenvlin[l * 1024 + k * 32 + j], a);
    if (t < 96) {
        int c = t >> 5, jj = t & 31;
        float b = 0.f;
        for (int tt = 0; tt < 64; ++tt) b = fmaf(s_inv[tt], Wprod[c * 2048 + tt * 32 + jj], b);
        s_ew[t] = b;
    }
    s_mix[t] = a;
    __syncthreads();
    float s = s_mix[j];
    float p = s_mix[t] * (s_ew[j] + s_ew[32 + j] * s + s_ew[64 + j] * s * s);
    __syncthreads();
    s_env[t] = p;
    __syncthreads();
    float o = 0.f;
    for (int jl = 0; jl < 32; ++jl) o = fmaf(s_env[m * 32 + jl], Wfeat[l * 1024 + jl * 32 + j], o);
    featOut[(size_t)n * 288 + t] = o;
}

// ---------------------------------------------------------------- K3: lat0 -> lat1 -> (lat1@Wenv1) + scatter [+ persist lat1h,w0h]
__global__ __launch_bounds__(256) void k3_update_scatter1(
    const float* __restrict__ nodeinv, const float* __restrict__ edgeinv,
    const float* __restrict__ elen, const float* __restrict__ edge_attr,
    const int* __restrict__ eidx, const _Float16* __restrict__ W2aT,
    const _Float16* __restrict__ W2bT, const _Float16* __restrict__ Wl1aT,
    const _Float16* __restrict__ Wl1bT, const _Float16* __restrict__ Wenv1T,
    const _Float16* __restrict__ Wenv0aT, const float* __restrict__ featN0,
    float* __restrict__ env, _Float16* __restrict__ lat1h,
    _Float16* __restrict__ w0h) {
    __shared__ alignas(16) _Float16 Ah[EB * AST];
    __shared__ alignas(16) _Float16 AhB[EB * BST];
    __shared__ float s_cut[EB];
    float* s_w = (float*)AhB;
    int t = threadIdx.x;
    int e0 = blockIdx.x * EB;
    int wave = t >> 6, lane = t & 63, r = lane & 15, g = lane >> 4;
    gather_latin(nodeinv, edgeinv, elen, eidx, e0, t, Ah, s_cut);
    gather_lnorm(featN0, eidx, e0, t, Ah);
    __syncthreads();
    lat0_mfma2(W2aT, W2bT, t, Ah, AhB, s_cut);
    f32x4 acc0[4], acc1[4];
    if (w0h) {  // w0 = lat0 @ Wenv0[:,0:96] (lat0 still in Ah)
        mfma_gemm2<6>(8, Ah, AST, Wenv0aT, t, acc0, acc1);
#pragma unroll
        for (int i = 0; i < 2; ++i) {
            int nt = wave + 4 * i;
            if (nt < 6) {
#pragma unroll
                for (int i2 = 0; i2 < 4; ++i2) {
                    w0h[(size_t)(e0 + g * 4 + i2) * 96 + nt * 16 + r] = (_Float16)acc0[i][i2];
                    w0h[(size_t)(e0 + 16 + g * 4 + i2) * 96 + nt * 16 + r] = (_Float16)acc1[i][i2];
                }
            }
        }
    }
    mfma_gemm2<16>(11, Ah, AST, Wl1aT, t, acc0, acc1);
#pragma unroll
    for (int i = 0; i < 4; ++i) {
        int nt = wave + 4 * i;
#pragma unroll
        for (int i2 = 0; i2 < 4; ++i2) {
            AhB[(g * 4 + i2) * BST + nt * 16 + r] = (_Float16)silu(acc0[i][i2]);
            AhB[(16 + g * 4 + i2) * BST + nt * 16 + r] = (_Float16)silu(acc1[i][i2]);
        }
    }
    __syncthreads();
    mfma_gemm2<16>(8, AhB, BST, Wl1bT, t, acc0, acc1);
#pragma unroll
    for (int i = 0; i < 4; ++i) {
        int nt = wave + 4 * i;
#pragma unroll
        for (int i2 = 0; i2 < 4; ++i2) {
            int ro = g * 4 + i2, col = nt * 16 + r;
            float v0 = 0.8944271909999159f * (float)Ah[ro * AST + col] +
                       0.4472135954999579f * s_cut[ro] * silu(acc0[i][i2]);
            _Float16 h0 = (_Float16)v0;
            Ah[ro * AST + col] = h0;
            float v1 = 0.8944271909999159f * (float)Ah[(16 + ro) * AST + col] +
                       0.4472135954999579f * s_cut[16 + ro] * silu(acc1[i][i2]);
            _Float16 h1 = (_Float16)v1;
            Ah[(16 + ro) * AST + col] = h1;
            if (lat1h) {
                lat1h[(size_t)(e0 + ro) * 256 + col] = h0;
                lat1h[(size_t)(e0 + 16 + ro) * 256 + col] = h1;
            }
        }
    }
    __syncthreads();
    mfma_gemm2<6>(8, Ah, AST, Wenv1T, t, acc0, acc1);
    epi6_f32(acc0, acc1, t, s_w);
    __syncthreads();
    scatter_env(edge_attr, eidx, s_w, s_cut, e0, t, env);
}

// ---------------------------------------------------------------- K5 slow (fallback): recompute path
__global__ __launch_bounds__(256) void k5_final(
    const float* __restrict__ nodeinv, const float* __restrict__ edgeinv,
    const float* __restrict__ elen, const float* __restrict__ edge_attr,
    const int* __restrict__ eidx, const _Float16* __restrict__ W2aT,
    const _Float16* __restrict__ W2bT, const _Float16* __restrict__ Wenv0aT,
    const _Float16* __restrict__ Wl1aT, const _Float16* __restrict__ Wl1bT,
    const _Float16* __restrict__ Bfin, const _Float16* __restrict__ Wro1T,
    const float* __restrict__ Wro2, const float* __restrict__ featN0,
    const float* __restrict__ featN1, float* __restrict__ out) {
    __shared__ alignas(16) _Float16 Ah[EB * AST];
    __shared__ alignas(16) _Float16 AhB[EB * BST];
    __shared__ alignas(16) _Float16 s_w0h[EB * 96];
    __shared__ float s_cut[EB];
    __shared__ float s_ps[EB][4];
    float* s_S = (float*)AhB;
    int t = threadIdx.x;
    int e0 = blockIdx.x * EB;
    int wave = t >> 6, lane = t & 63, r = lane & 15, g = lane >> 4;
    gather_latin(nodeinv, edgeinv, elen, eidx, e0, t, Ah, s_cut);
    gather_lnorm(featN0, eidx, e0, t, Ah);
    __syncthreads();
    lat0_mfma2(W2aT, W2bT, t, Ah, AhB, s_cut);
    f32x4 acc0[4], acc1[4];
    mfma_gemm2<6>(8, Ah, AST, Wenv0aT, t, acc0, acc1);
#pragma unroll
    for (int i = 0; i < 2; ++i) {
        int nt = wave + 4 * i;
        if (nt < 6) {
#pragma unroll
            for (int i2 = 0; i2 < 4; ++i2) {
                s_w0h[(g * 4 + i2) * 96 + nt * 16 + r] = (_Float16)acc0[i][i2];
                s_w0h[(16 + g * 4 + i2) * 96 + nt * 16 + r] = (_Float16)acc1[i][i2];
            }
        }
    }
    mfma_gemm2<16>(11, Ah, AST, Wl1aT, t, acc0, acc1);
#pragma unroll
    for (int i = 0; i < 4; ++i) {
        int nt = wave + 4 * i;
#pragma unroll
        for (int i2 = 0; i2 < 4; ++i2) {
            AhB[(g * 4 + i2) * BST + nt * 16 + r] = (_Float16)silu(acc0[i][i2]);
            AhB[(16 + g * 4 + i2) * BST + nt * 16 + r] = (_Float16)silu(acc1[i][i2]);
        }
    }
    __syncthreads();
    mfma_gemm2<16>(8, AhB, BST, Wl1bT, t, acc0, acc1);
#pragma unroll
    for (int i = 0; i < 4; ++i) {
        int nt = wave + 4 * i;
#pragma unroll
        for (int i2 = 0; i2 < 4; ++i2) {
            int ro = g * 4 + i2, col = nt * 16 + r;
            float v0 = 0.8944271909999159f * (float)Ah[ro * AST + col] +
                       0.4472135954999579f * s_cut[ro] * silu(acc0[i][i2]);
            Ah[ro * AST + col] = (_Float16)v0;
            float v1 = 0.8944271909999159f * (float)Ah[(16 + ro) * AST + col] +
                       0.4472135954999579f * s_cut[16 + ro] * silu(acc1[i][i2]);
            Ah[(16 + ro) * AST + col] = (_Float16)v1;
        }
    }
    __syncthreads();
    for (int i = t; i < EB * 96; i += 256) {
        int ee = i / 96, rem = i - ee * 96;
        int l = rem >> 5, kk = rem & 31;
        int off = (l == 0) ? 0 : ((l == 1) ? 1 : 4);
        int d = (l == 0) ? 1 : ((l == 1) ? 3 : 5);
        int e = e0 + ee;
        const float* f = featN1 + (size_t)eidx[e] * 288 + kk;
        float s = 0.f;
        for (int mm = off; mm < off + d; ++mm)
            s = fmaf(f[mm * 32], edge_attr[(size_t)e * 9 + mm], s);
        s_S[ee * 96 + rem] = s;
    }
    __syncthreads();
    {
        int n15 = lane & 15, g8 = lane >> 4, mb = g8 * 4;
        f16x8 a0[8], a1[8];
#pragma unroll
        for (int cc = 0; cc < 8; ++cc) {
            a0[cc] = *(const f16x8*)(Ah + n15 * AST + cc * 32 + g8 * 8);
            a1[cc] = *(const f16x8*)(Ah + (16 + n15) * AST + cc * 32 + g8 * 8);
        }
        int ncombo = (wave < 2) ? 2 : 1;
        for (int ci = 0; ci < ncombo; ++ci) {
            int combo = wave + ci * 4;
            int l = combo >> 1, j0 = (combo & 1) * 16;
            f32x4 run0 = {0.f, 0.f, 0.f, 0.f}, run1 = {0.f, 0.f, 0.f, 0.f};
            for (int ke = 0; ke < 32; ++ke) {
                const _Float16* bb = Bfin + (size_t)(combo * 32 + ke) * 4096 + lane * 8;
                f32x4 ac0 = {0.f, 0.f, 0.f, 0.f}, ac1 = {0.f, 0.f, 0.f, 0.f};
#pragma unroll
                for (int cc = 0; cc < 8; ++cc) {
                    f16x8 b = *(const f16x8*)(bb + cc * 512);
                    ac0 = __builtin_amdgcn_mfma_f32_16x16x32_f16(a0[cc], b, ac0, 0, 0, 0);
                    ac1 = __builtin_amdgcn_mfma_f32_16x16x32_f16(a1[cc], b, ac1, 0, 0, 0);
                }
#pragma unroll
                for (int i2 = 0; i2 < 4; ++i2) {
                    run0[i2] = fmaf(ac0[i2], s_S[(mb + i2) * 96 + l * 32 + ke], run0[i2]);
                    run1[i2] = fmaf(ac1[i2], s_S[(16 + mb + i2) * 96 + l * 32 + ke], run1[i2]);
                }
            }
#pragma unroll
            for (int i2 = 0; i2 < 4; ++i2) {
                int jo = j0 + n15;
                Ah[(mb + i2) * AST + 256 + l * 32 + jo] =
                    (_Float16)((float)s_w0h[(mb + i2) * 96 + jo * 3 + l] * run0[i2]);
                Ah[(16 + mb + i2) * AST + 256 + l * 32 + jo] =
                    (_Float16)((float)s_w0h[(16 + mb + i2) * 96 + jo * 3 + l] * run1[i2]);
            }
        }
    }
    __syncthreads();
    mfma_gemm2<16>(11, Ah, AST, Wro1T, t, acc0, acc1);
    float v0[4] = {0.f, 0.f, 0.f, 0.f}, v1[4] = {0.f, 0.f, 0.f, 0.f};
#pragma unroll
    for (int i = 0; i < 4; ++i) {
        int col = (wave + 4 * i) * 16 + r;
        float w2 = Wro2[col];
#pragma unroll
        for (int i2 = 0; i2 < 4; ++i2) {
            v0[i2] += silu(acc0[i][i2]) * w2;
            v1[i2] += silu(acc1[i][i2]) * w2;
        }
    }
#pragma unroll
    for (int off = 1; off < 16; off <<= 1) {
#pragma unroll
        for (int i2 = 0; i2 < 4; ++i2) {
            v0[i2] += __shfl_xor(v0[i2], off);
            v1[i2] += __shfl_xor(v1[i2], off);
        }
    }
    if (r == 0) {
#pragma unroll
        for (int i2 = 0; i2 < 4; ++i2) {
            s_ps[g * 4 + i2][wave] = v0[i2];
            s_ps[16 + g * 4 + i2][wave] = v1[i2];
        }
    }
    __syncthreads();
    if (t < EB) out[e0 + t] = s_ps[t][0] + s_ps[t][1] + s_ps[t][2] + s_ps[t][3];
}

// ---------------------------------------------------------------- K5 fast: 8 waves, 2 m-tiles/wave, static reg indexing
#define FEB 64
__global__ __launch_bounds__(512) void k5_fast(
    const float* __restrict__ edge_attr, const int* __restrict__ eidx,
    const _Float16* __restrict__ lat1h, const _Float16* __restrict__ w0h,
    const _Float16* __restrict__ Bfin, const _Float16* __restrict__ Wro1T,
    const float* __restrict__ Wro2, const float* __restrict__ featN1,
    float* __restrict__ out) {
    __shared__ alignas(16) _Float16 s_S[FEB * 96];  // S (f16), later scal-f16
    __shared__ float s_scal[FEB * 96];
    __shared__ float s_ps[FEB][4];
    int t = threadIdx.x;
    int e0 = blockIdx.x * FEB;
    int wave = t >> 6, lane = t & 63, r = lane & 15, g8 = lane >> 4;
    int mh = wave >> 2, w4 = wave & 3;   // edge-half, wave-within-half
    int eh = e0 + mh * 32;
    for (int i = t; i < FEB * 96; i += 512) s_scal[i] = 0.f;
    // S[e,l,k]
    for (int i = t; i < FEB * 96; i += 512) {
        int ee = i / 96, rem = i - ee * 96;
        int l = rem >> 5, kk = rem & 31;
        int off = (l == 0) ? 0 : ((l == 1) ? 1 : 4);
        int d = (l == 0) ? 1 : ((l == 1) ? 3 : 5);
        int e = e0 + ee;
        const float* f = featN1 + (size_t)eidx[e] * 288 + kk;
        float s = 0.f;
        for (int mm = off; mm < off + d; ++mm)
            s = fmaf(f[mm * 32], edge_attr[(size_t)e * 9 + mm], s);
        s_S[i] = (_Float16)s;
    }
    // A-frags (lat1): 2 m-tiles per wave (64 VGPR), reused by contraction AND readout
    f16x8 a[2][8];
#pragma unroll
    for (int mt = 0; mt < 2; ++mt)
#pragma unroll
        for (int cc = 0; cc < 8; ++cc)
            a[mt][cc] = *(const f16x8*)(lat1h + (size_t)(eh + mt * 16 + r) * 256 +
                                        cc * 32 + g8 * 8);
    __syncthreads();
    // 12 units per half: (combo, ke-half); this wave does 3
#pragma unroll 1
    for (int ui = 0; ui < 3; ++ui) {
        int u = w4 + 4 * ui;
        int combo = u >> 1, kh = u & 1;
        int l = combo >> 1, j0 = (combo & 1) * 16;
        f32x4 run[2];
#pragma unroll
        for (int mt = 0; mt < 2; ++mt) run[mt] = (f32x4){0.f, 0.f, 0.f, 0.f};
        for (int kei = 0; kei < 16; ++kei) {
            int ke = kh * 16 + kei;
            const _Float16* bb = Bfin + (size_t)(combo * 32 + ke) * 4096 + lane * 8;
            f32x4 ac[2];
#pragma unroll
            for (int mt = 0; mt < 2; ++mt) ac[mt] = (f32x4){0.f, 0.f, 0.f, 0.f};
#pragma unroll
            for (int cc = 0; cc < 8; ++cc) {
                f16x8 b = *(const f16x8*)(bb + cc * 512);
                ac[0] = __builtin_amdgcn_mfma_f32_16x16x32_f16(a[0][cc], b, ac[0], 0, 0, 0);
                ac[1] = __builtin_amdgcn_mfma_f32_16x16x32_f16(a[1][cc], b, ac[1], 0, 0, 0);
            }
#pragma unroll
            for (int mt = 0; mt < 2; ++mt)
#pragma unroll
                for (int i2 = 0; i2 < 4; ++i2)
                    run[mt][i2] = fmaf(ac[mt][i2],
                                       (float)s_S[(mh * 32 + mt * 16 + g8 * 4 + i2) * 96 + l * 32 + ke],
                                       run[mt][i2]);
        }
#pragma unroll
        for (int mt = 0; mt < 2; ++mt)
#pragma unroll
            for (int i2 = 0; i2 < 4; ++i2)
                atomicAdd(&s_scal[(mh * 32 + mt * 16 + g8 * 4 + i2) * 96 + l * 32 + j0 + r],
                          run[mt][i2]);
    }
    __syncthreads();
    // apply w0, produce scal-f16 into s_S (dead)
    for (int i = t; i < FEB * 96; i += 512) {
        int m = i / 96, rem = i - m * 96;
        int l = rem >> 5, jo = rem & 31;
        float w0 = (float)w0h[(size_t)(e0 + m) * 96 + jo * 3 + l];
        s_S[i] = (_Float16)(s_scal[i] * w0);
    }
    __syncthreads();
    // readout: A cols 0..255 from regs (a), 256..351 from s_S  (ks fully unrolled: static a-index)
    f32x4 racc[4][2];
#pragma unroll
    for (int i = 0; i < 4; ++i)
#pragma unroll
        for (int mt = 0; mt < 2; ++mt) racc[i][mt] = (f32x4){0.f, 0.f, 0.f, 0.f};
#pragma unroll
    for (int ks = 0; ks < 11; ++ks) {
        f16x8 af0 = (ks < 8) ? a[0][ks]
                             : *(const f16x8*)(s_S + (mh * 32 + r) * 96 + (ks - 8) * 32 + g8 * 8);
        f16x8 af1 = (ks < 8) ? a[1][ks]
                             : *(const f16x8*)(s_S + (mh * 32 + 16 + r) * 96 + (ks - 8) * 32 + g8 * 8);
#pragma unroll
        for (int i = 0; i < 4; ++i) {
            int nt = w4 + 4 * i;
            f16x8 b = *(const f16x8*)(Wro1T + ((size_t)(nt * 11 + ks) * 64 + lane) * 8);
            racc[i][0] = __builtin_amdgcn_mfma_f32_16x16x32_f16(af0, b, racc[i][0], 0, 0, 0);
            racc[i][1] = __builtin_amdgcn_mfma_f32_16x16x32_f16(af1, b, racc[i][1], 0, 0, 0);
        }
    }
    float v[2][4];
#pragma unroll
    for (int mt = 0; mt < 2; ++mt)
#pragma unroll
        for (int i2 = 0; i2 < 4; ++i2) v[mt][i2] = 0.f;
#pragma unroll
    for (int i = 0; i < 4; ++i) {
        int col = (w4 + 4 * i) * 16 + r;
        float w2 = Wro2[col];
#pragma unroll
        for (int mt = 0; mt < 2; ++mt)
#pragma unroll
            for (int i2 = 0; i2 < 4; ++i2) v[mt][i2] += silu(racc[i][mt][i2]) * w2;
    }
#pragma unroll
    for (int off = 1; off < 16; off <<= 1)
#pragma unroll
        for (int mt = 0; mt < 2; ++mt)
#pragma unroll
            for (int i2 = 0; i2 < 4; ++i2) v[mt][i2] += __shfl_xor(v[mt][i2], off);
    if (r == 0) {
#pragma unroll
        for (int mt = 0; mt < 2; ++mt)
#pragma unroll
            for (int i2 = 0; i2 < 4; ++i2)
                s_ps[mh * 32 + mt * 16 + g8 * 4 + i2][w4] = v[mt][i2];
    }
    __syncthreads();
    if (t < FEB) out[e0 + t] = s_ps[t][0] + s_ps[t][1] + s_ps[t][2] + s_ps[t][3];
}

// ----------------------------------------------------------------
extern "C" void kernel_launch(void* const* d_in, const int* in_sizes, int n_in,
                              void* d_out, int out_size, void* d_ws, size_t ws_size,
                              hipStream_t stream) {
    (void)in_sizes; (void)n_in; (void)out_size;
    const float* edge_attr = (const float*)d_in[0];
    const float* edge_len  = (const float*)d_in[1];
    const float* edge_inv  = (const float*)d_in[2];
    const float* node_inv  = (const float*)d_in[3];
    const float* W2a     = (const float*)d_in[4];
    const float* W2b     = (const float*)d_in[5];
    const float* Wl1a    = (const float*)d_in[6];
    const float* Wl1b    = (const float*)d_in[7];
    const float* Wenv0   = (const float*)d_in[8];
    const float* Wenv1   = (const float*)d_in[9];
    const float* Wenvlin = (const float*)d_in[10];
    const float* Wprod   = (const float*)d_in[11];
    const float* Wfeat   = (const float*)d_in[12];
    const float* Wfinlat = (const float*)d_in[13];
    const float* Wro1    = (const float*)d_in[14];
    const float* Wro2    = (const float*)d_in[15];
    const int* eidx      = (const int*)d_in[16];
    float* out = (float*)d_out;

    _Float16* p = (_Float16*)d_ws;
    _Float16* Bfin    = p; p += 786432;
    _Float16* W2aT    = p; p += 40960;
    _Float16* W2bT    = p; p += 65536;
    _Float16* Wenv0aT = p; p += 24576;
    _Float16* Wenv0bT = p; p += 24576;
    _Float16* Wenv1T  = p; p += 24576;
    _Float16* Wl1aT   = p; p += 90112;
    _Float16* Wl1bT   = p; p += 65536;
    _Float16* Wro1T   = p; p += 90112;
    float* env    = (float*)p;
    float* featN0 = env + (size_t)NNODES * 288;
    char* after = (char*)(featN0 + (size_t)NNODES * 288);
    size_t need_slow = (size_t)(after - (char*)d_ws);
    if (ws_size < need_slow) return;
    _Float16* lat1h = (_Float16*)after;                       // NE*256 f16
    _Float16* w0h   = lat1h + (size_t)NE * 256;               // NE*96 f16
    size_t need_fast = need_slow + (size_t)NE * (256 + 96) * sizeof(_Float16);
    bool fast = (ws_size >= need_fast);
    if (!fast) { lat1h = nullptr; w0h = nullptr; }

    const int ENV_N = NNODES * 288;
    k_packfin<<<3072, 256, 0, stream>>>(Wfinlat, Bfin);
    k_packf<<<160, 256, 0, stream>>>(W2a, W2aT, 136, 5, 16, 256, 0);
    k_packf<<<256, 256, 0, stream>>>(W2b, W2bT, 256, 8, 16, 256, 0);
    k_packf<<<96, 256, 0, stream>>>(Wenv0, Wenv0aT, 256, 8, 6, 192, 0);
    k_packf<<<96, 256, 0, stream>>>(Wenv0, Wenv0bT, 256, 8, 6, 192, 96);
    k_packf<<<96, 256, 0, stream>>>(Wenv1, Wenv1T, 256, 8, 6, 96, 0);
    k_packf<<<352, 256, 0, stream>>>(Wl1a, Wl1aT, 352, 11, 16, 256, 0);
    k_packf<<<256, 256, 0, stream>>>(Wl1b, Wl1bT, 256, 8, 16, 256, 0);
    k_packf<<<352, 256, 0, stream>>>(Wro1, Wro1T, 352, 11, 16, 256, 0);

    k_zero<<<(ENV_N + 255) / 256, 256, 0, stream>>>(env, ENV_N);
    k1_lat_scatter0<<<NBLK, 256, 0, stream>>>(node_inv, edge_inv, edge_len, edge_attr,
                                              eidx, W2aT, W2bT, Wenv0bT, env);
    k_node<<<NNODES, 288, 0, stream>>>(env, node_inv, Wenvlin, Wprod, Wfeat, featN0);
    k_zero<<<(ENV_N + 255) / 256, 256, 0, stream>>>(env, ENV_N);
    k3_update_scatter1<<<NBLK, 256, 0, stream>>>(node_inv, edge_inv, edge_len, edge_attr,
                                                 eidx, W2aT, W2bT, Wl1aT, Wl1bT, Wenv1T,
                                                 Wenv0aT, featN0, env, lat1h, w0h);
    k_node<<<NNODES, 288, 0, stream>>>(env, node_inv, Wenvlin + 3072, Wprod + 6144,
                                       Wfeat + 3072, env);  // in-place: env1 -> featN1
    if (fast) {
        k5_fast<<<NE / FEB, 512, 0, stream>>>(edge_attr, eidx, lat1h, w0h, Bfin, Wro1T,
                                              Wro2, env, out);
    } else {
        k5_final<<<NBLK, 256, 0, stream>>>(node_inv, edge_inv, edge_len, edge_attr, eidx,
                                           W2aT, W2bT, Wenv0aT, Wl1aT, Wl1bT, Bfin, Wro1T,
                                           Wro2, featN0, env, out);
    }
}

// Round 9
// 4707.437 us; speedup vs baseline: 1.0703x; 1.0703x over previous
//
#include <hip/hip_runtime.h>
#include <math.h>

#define NE 320000
#define NNODES 10000
#define EB 32
#define NBLK (NE / EB)
#define AST 360   // Ah stride (f16 elems)
#define BST 264   // AhB stride (f16 elems)
#define SST 98    // padded S stride (f16) -> conflict-free per-row u16 reads

typedef _Float16 f16x8 __attribute__((ext_vector_type(8)));
typedef float f32x4 __attribute__((ext_vector_type(4)));
typedef float f32x16 __attribute__((ext_vector_type(16)));

__device__ __forceinline__ float silu(float x) { return x / (1.0f + __expf(-x)); }
__device__ __forceinline__ float cutf(float len) {
    float x = len * (1.0f / 6.0f);
    float x2 = x * x, x6 = x2 * x2 * x2;
    float f = 1.0f - 28.0f * x6 + 48.0f * x6 * x - 21.0f * x6 * x2;
    return (x < 1.0f) ? f : 0.0f;
}

// ---------------------------------------------------------------- zero
__global__ __launch_bounds__(256) void k_zero(float* __restrict__ p, int n) {
    int i = blockIdx.x * 256 + threadIdx.x;
    if (i < n) p[i] = 0.f;
}

// ---------------------------------------------------------------- fragment-major pack for MLP weights
__global__ __launch_bounds__(256) void k_packf(const float* __restrict__ src,
                                               _Float16* __restrict__ dst,
                                               int K, int KS, int NT, int stride,
                                               int colOff) {
    int i = blockIdx.x * 256 + threadIdx.x;
    if (i >= NT * KS * 512) return;
    int j = i & 7, lane = (i >> 3) & 63;
    int blk = i >> 9;
    int ks = blk % KS, nt = blk / KS;
    int k = ks * 32 + (lane >> 4) * 8 + j;
    int n = colOff + nt * 16 + (lane & 15);
    dst[i] = (k < K) ? (_Float16)src[(size_t)k * stride + n] : (_Float16)0.f;
}

// ---------------------------------------------------------------- old fragment-major pack of Wfinlat (fallback path)
__global__ __launch_bounds__(256) void k_packfin(const float* __restrict__ W,
                                                 _Float16* __restrict__ dst) {
    int i = blockIdx.x * 256 + threadIdx.x;  // < 786432
    int j = i & 7, lane = (i >> 3) & 63, cc = (i >> 9) & 7, ke = (i >> 12) & 31,
        combo = i >> 17;
    int n = (combo >> 1) * 1024 + ke * 32 + (combo & 1) * 16 + (lane & 15);
    int c = cc * 32 + (lane >> 4) * 8 + j;
    dst[i] = (_Float16)W[(size_t)c * 3072 + n];
}

// ---------------------------------------------------------------- stage-major pack of Wfinlat for 32x32x16 pipeline
// stage s = l*32+ke (96 stages of 8192 f16 = 16KB); within stage:
// dst[s*8192 + cs*512 + lane*8 + j] = Wfin[c = cs*16+(lane>>5)*8+j][l*1024+ke*32+(lane&31)]
__global__ __launch_bounds__(256) void k_packfin3(const float* __restrict__ W,
                                                  _Float16* __restrict__ dst) {
    int i = blockIdx.x * 256 + threadIdx.x;  // < 786432
    int j = i & 7, lane = (i >> 3) & 63, cs = (i >> 9) & 15, s = i >> 13;
    int l = s >> 5, ke = s & 31;
    int c = cs * 16 + (lane >> 5) * 8 + j;
    int n = l * 1024 + ke * 32 + (lane & 31);
    dst[i] = (_Float16)W[(size_t)c * 3072 + n];
}

// ---------------------------------------------------------------- MFMA GEMM, 32 edges (2 m-tiles), frag-major B
template <int NT>
__device__ __forceinline__ void mfma_gemm2(int ksteps, const _Float16* Ah, int astride,
                                           const _Float16* __restrict__ Wt, int t,
                                           f32x4* acc0, f32x4* acc1) {
    int wave = t >> 6, lane = t & 63, r = lane & 15, g = lane >> 4;
    const int TPW = (NT + 3) / 4;
#pragma unroll
    for (int i = 0; i < TPW; ++i) {
        acc0[i] = (f32x4){0.f, 0.f, 0.f, 0.f};
        acc1[i] = (f32x4){0.f, 0.f, 0.f, 0.f};
    }
    for (int ks = 0; ks < ksteps; ++ks) {
        f16x8 a0 = *(const f16x8*)(Ah + r * astride + ks * 32 + g * 8);
        f16x8 a1 = *(const f16x8*)(Ah + (16 + r) * astride + ks * 32 + g * 8);
#pragma unroll
        for (int i = 0; i < TPW; ++i) {
            int nt = wave + 4 * i;
            if (nt < NT) {
                f16x8 b = *(const f16x8*)(Wt + ((size_t)(nt * ksteps + ks) * 64 + lane) * 8);
                acc0[i] = __builtin_amdgcn_mfma_f32_16x16x32_f16(a0, b, acc0[i], 0, 0, 0);
                acc1[i] = __builtin_amdgcn_mfma_f32_16x16x32_f16(a1, b, acc1[i], 0, 0, 0);
            }
        }
    }
}

// gather lat_in -> Ah cols 0..159 (f16), compute s_cut
__device__ __forceinline__ void gather_latin(
    const float* __restrict__ nodeinv, const float* __restrict__ edgeinv,
    const float* __restrict__ elen, const int* __restrict__ eidx,
    int e0, int t, _Float16* Ah, float* s_cut) {
    if (t < EB) s_cut[t] = cutf(elen[e0 + t]);
    for (int i = t; i < EB * 160; i += 256) {
        int ee = i / 160, k = i - ee * 160;
        int e = e0 + ee;
        float v;
        if (k < 64)       v = nodeinv[eidx[e] * 64 + k];
        else if (k < 128) v = nodeinv[eidx[NE + e] * 64 + (k - 64)];
        else if (k < 136) v = edgeinv[(size_t)e * 8 + (k - 128)];
        else              v = 0.f;
        Ah[ee * AST + k] = (_Float16)v;
    }
}

// lat0 (2 GEMMs) -> Ah cols 0..255 f16
__device__ __forceinline__ void lat0_mfma2(const _Float16* __restrict__ W2aT,
                                           const _Float16* __restrict__ W2bT,
                                           int t, _Float16* Ah, _Float16* AhB,
                                           const float* s_cut) {
    int wave = t >> 6, lane = t & 63, r = lane & 15, g = lane >> 4;
    f32x4 acc0[4], acc1[4];
    mfma_gemm2<16>(5, Ah, AST, W2aT, t, acc0, acc1);
#pragma unroll
    for (int i = 0; i < 4; ++i) {
        int nt = wave + 4 * i;
#pragma unroll
        for (int i2 = 0; i2 < 4; ++i2) {
            AhB[(g * 4 + i2) * BST + nt * 16 + r] = (_Float16)silu(acc0[i][i2]);
            AhB[(16 + g * 4 + i2) * BST + nt * 16 + r] = (_Float16)silu(acc1[i][i2]);
        }
    }
    __syncthreads();
    mfma_gemm2<16>(8, AhB, BST, W2bT, t, acc0, acc1);
#pragma unroll
    for (int i = 0; i < 4; ++i) {
        int nt = wave + 4 * i;
#pragma unroll
        for (int i2 = 0; i2 < 4; ++i2) {
            int ro = g * 4 + i2, col = nt * 16 + r;
            Ah[ro * AST + col] = (_Float16)(s_cut[ro] * silu(acc0[i][i2]));
            Ah[(16 + ro) * AST + col] = (_Float16)(s_cut[16 + ro] * silu(acc1[i][i2]));
        }
    }
    __syncthreads();
}

// lnorm(featN[center]) -> Ah cols 256..351 f16
__device__ __forceinline__ void gather_lnorm(const float* __restrict__ featN,
                                             const int* __restrict__ eidx,
                                             int e0, int t, _Float16* Ah) {
    for (int i = t; i < EB * 96; i += 256) {
        int ee = i / 96, rem = i - ee * 96;
        int l = rem >> 5, kk = rem & 31;
        int off = (l == 0) ? 0 : ((l == 1) ? 1 : 4);
        int d = (l == 0) ? 1 : ((l == 1) ? 3 : 5);
        const float* f = featN + (size_t)eidx[e0 + ee] * 288 + kk;
        float s = 1e-8f;
        for (int mm = off; mm < off + d; ++mm) { float x = f[mm * 32]; s = fmaf(x, x, s); }
        Ah[ee * AST + 256 + rem] = (_Float16)sqrtf(s);
    }
}

// scatter env += weight_channels(sh, s_w)*cut  (s_w f32 [EB][96])
__device__ __forceinline__ void scatter_env(const float* __restrict__ edge_attr,
                                            const int* __restrict__ eidx,
                                            const float* s_w, const float* s_cut,
                                            int e0, int t, float* __restrict__ env) {
    for (int i = t; i < EB * 32; i += 256) {
        int el = i >> 5, k = i & 31;
        int e = e0 + el;
        float cw = s_cut[el];
        int n = eidx[e];
        float w0 = s_w[el * 96 + k * 3 + 0] * cw;
        float w1 = s_w[el * 96 + k * 3 + 1] * cw;
        float w2 = s_w[el * 96 + k * 3 + 2] * cw;
        float* dst = env + (size_t)n * 288 + k;
#pragma unroll
        for (int m = 0; m < 9; ++m) {
            float w = (m == 0) ? w0 : ((m < 4) ? w1 : w2);
            atomicAdd(dst + m * 32, edge_attr[(size_t)e * 9 + m] * w);
        }
    }
}

// NT=6 epilogue -> s_w (f32)
__device__ __forceinline__ void epi6_f32(const f32x4* acc0, const f32x4* acc1, int t,
                                         float* s_w) {
    int wave = t >> 6, lane = t & 63, r = lane & 15, g = lane >> 4;
#pragma unroll
    for (int i = 0; i < 2; ++i) {
        int nt = wave + 4 * i;
        if (nt < 6) {
#pragma unroll
            for (int i2 = 0; i2 < 4; ++i2) {
                s_w[(g * 4 + i2) * 96 + nt * 16 + r] = acc0[i][i2];
                s_w[(16 + g * 4 + i2) * 96 + nt * 16 + r] = acc1[i][i2];
            }
        }
    }
}

// ---------------------------------------------------------------- K1: lat0 + (lat0@Wenv0b) + scatter
__global__ __launch_bounds__(256) void k1_lat_scatter0(
    const float* __restrict__ nodeinv, const float* __restrict__ edgeinv,
    const float* __restrict__ elen, const float* __restrict__ edge_attr,
    const int* __restrict__ eidx, const _Float16* __restrict__ W2aT,
    const _Float16* __restrict__ W2bT, const _Float16* __restrict__ Wenv0bT,
    float* __restrict__ env) {
    __shared__ alignas(16) _Float16 Ah[EB * AST];
    __shared__ alignas(16) _Float16 AhB[EB * BST];
    __shared__ float s_cut[EB];
    float* s_w = (float*)AhB;  // overlay: AhB dead after lat0
    int t = threadIdx.x;
    int e0 = blockIdx.x * EB;
    gather_latin(nodeinv, edgeinv, elen, eidx, e0, t, Ah, s_cut);
    __syncthreads();
    lat0_mfma2(W2aT, W2bT, t, Ah, AhB, s_cut);
    f32x4 acc0[4], acc1[4];
    mfma_gemm2<6>(8, Ah, AST, Wenv0bT, t, acc0, acc1);
    epi6_f32(acc0, acc1, t, s_w);
    __syncthreads();
    scatter_env(edge_attr, eidx, s_w, s_cut, e0, t, env);
}

// ---------------------------------------------------------------- node transform (unchanged)
__global__ __launch_bounds__(288) void k_node(
    const float* envin, const float* __restrict__ nodeinv,
    const float* __restrict__ Wenvlin, const float* __restrict__ Wprod,
    const float* __restrict__ Wfeat, float* featOut) {
    __shared__ float s_env[288];
    __shared__ float s_inv[64];
    __shared__ float s_mix[288];
    __shared__ float s_ew[96];
    int n = blockIdx.x;
    int t = threadIdx.x;
    s_env[t] = envin[(size_t)n * 288 + t] * (1.0f / 32.0f);
    if (t < 64) s_inv[t] = nodeinv[n * 64 + t];
    __syncthreads();
    int m = t >> 5, j = t & 31;
    int l = (m == 0) ? 0 : ((m < 4) ? 1 : 2);
    float a = 0.f;
    for (int k = 0; k < 32; ++k) a = fmaf(s_env[m * 32 + k], Wenvlin[l * 1024 + k * 32 + j], a);
    if (t < 96) {
        int c = t >> 5, jj = t & 31;
        float b = 0.f;
        for (int tt = 0; tt < 64; ++tt) b = fmaf(s_inv[tt], Wprod[c * 2048 + tt * 32 + jj], b);
        s_ew[t] = b;
    }
    s_mix[t] = a;
    __syncthreads();
    float s = s_mix[j];
    float p = s_mix[t] * (s_ew[j] + s_ew[32 + j] * s + s_ew[64 + j] * s * s);
    __syncthreads();
    s_env[t] = p;
    __syncthreads();
    float o = 0.f;
    for (int jl = 0; jl < 32; ++jl) o = fmaf(s_env[m * 32 + jl], Wfeat[l * 1024 + jl * 32 + j], o);
    featOut[(size_t)n * 288 + t] = o;
}

// ---------------------------------------------------------------- K3: lat0 -> lat1 -> (lat1@Wenv1) + scatter [+ persist lat1h,w0h]
__global__ __launch_bounds__(256) void k3_update_scatter1(
    const float* __restrict__ nodeinv, const float* __restrict__ edgeinv,
    const float* __restrict__ elen, const float* __restrict__ edge_attr,
    const int* __restrict__ eidx, const _Float16* __restrict__ W2aT,
    const _Float16* __restrict__ W2bT, const _Float16* __restrict__ Wl1aT,
    const _Float16* __restrict__ Wl1bT, const _Float16* __restrict__ Wenv1T,
    const _Float16* __restrict__ Wenv0aT, const float* __restrict__ featN0,
    float* __restrict__ env, _Float16* __restrict__ lat1h,
    _Float16* __restrict__ w0h) {
    __shared__ alignas(16) _Float16 Ah[EB * AST];
    __shared__ alignas(16) _Float16 AhB[EB * BST];
    __shared__ float s_cut[EB];
    float* s_w = (float*)AhB;
    int t = threadIdx.x;
    int e0 = blockIdx.x * EB;
    int wave = t >> 6, lane = t & 63, r = lane & 15, g = lane >> 4;
    gather_latin(nodeinv, edgeinv, elen, eidx, e0, t, Ah, s_cut);
    gather_lnorm(featN0, eidx, e0, t, Ah);
    __syncthreads();
    lat0_mfma2(W2aT, W2bT, t, Ah, AhB, s_cut);
    f32x4 acc0[4], acc1[4];
    if (w0h) {  // w0 = lat0 @ Wenv0[:,0:96] (lat0 still in Ah)
        mfma_gemm2<6>(8, Ah, AST, Wenv0aT, t, acc0, acc1);
#pragma unroll
        for (int i = 0; i < 2; ++i) {
            int nt = wave + 4 * i;
            if (nt < 6) {
#pragma unroll
                for (int i2 = 0; i2 < 4; ++i2) {
                    w0h[(size_t)(e0 + g * 4 + i2) * 96 + nt * 16 + r] = (_Float16)acc0[i][i2];
                    w0h[(size_t)(e0 + 16 + g * 4 + i2) * 96 + nt * 16 + r] = (_Float16)acc1[i][i2];
                }
            }
        }
    }
    mfma_gemm2<16>(11, Ah, AST, Wl1aT, t, acc0, acc1);
#pragma unroll
    for (int i = 0; i < 4; ++i) {
        int nt = wave + 4 * i;
#pragma unroll
        for (int i2 = 0; i2 < 4; ++i2) {
            AhB[(g * 4 + i2) * BST + nt * 16 + r] = (_Float16)silu(acc0[i][i2]);
            AhB[(16 + g * 4 + i2) * BST + nt * 16 + r] = (_Float16)silu(acc1[i][i2]);
        }
    }
    __syncthreads();
    mfma_gemm2<16>(8, AhB, BST, Wl1bT, t, acc0, acc1);
#pragma unroll
    for (int i = 0; i < 4; ++i) {
        int nt = wave + 4 * i;
#pragma unroll
        for (int i2 = 0; i2 < 4; ++i2) {
            int ro = g * 4 + i2, col = nt * 16 + r;
            float v0 = 0.8944271909999159f * (float)Ah[ro * AST + col] +
                       0.4472135954999579f * s_cut[ro] * silu(acc0[i][i2]);
            _Float16 h0 = (_Float16)v0;
            Ah[ro * AST + col] = h0;
            float v1 = 0.8944271909999159f * (float)Ah[(16 + ro) * AST + col] +
                       0.4472135954999579f * s_cut[16 + ro] * silu(acc1[i][i2]);
            _Float16 h1 = (_Float16)v1;
            Ah[(16 + ro) * AST + col] = h1;
            if (lat1h) {
                lat1h[(size_t)(e0 + ro) * 256 + col] = h0;
                lat1h[(size_t)(e0 + 16 + ro) * 256 + col] = h1;
            }
        }
    }
    __syncthreads();
    mfma_gemm2<6>(8, Ah, AST, Wenv1T, t, acc0, acc1);
    epi6_f32(acc0, acc1, t, s_w);
    __syncthreads();
    scatter_env(edge_attr, eidx, s_w, s_cut, e0, t, env);
}

// ---------------------------------------------------------------- K5 slow (fallback): recompute path (old Bfin layout)
__global__ __launch_bounds__(256) void k5_final(
    const float* __restrict__ nodeinv, const float* __restrict__ edgeinv,
    const float* __restrict__ elen, const float* __restrict__ edge_attr,
    const int* __restrict__ eidx, const _Float16* __restrict__ W2aT,
    const _Float16* __restrict__ W2bT, const _Float16* __restrict__ Wenv0aT,
    const _Float16* __restrict__ Wl1aT, const _Float16* __restrict__ Wl1bT,
    const _Float16* __restrict__ Bfin, const _Float16* __restrict__ Wro1T,
    const float* __restrict__ Wro2, const float* __restrict__ featN0,
    const float* __restrict__ featN1, float* __restrict__ out) {
    __shared__ alignas(16) _Float16 Ah[EB * AST];
    __shared__ alignas(16) _Float16 AhB[EB * BST];
    __shared__ alignas(16) _Float16 s_w0h[EB * 96];
    __shared__ float s_cut[EB];
    __shared__ float s_ps[EB][4];
    float* s_S = (float*)AhB;
    int t = threadIdx.x;
    int e0 = blockIdx.x * EB;
    int wave = t >> 6, lane = t & 63, r = lane & 15, g = lane >> 4;
    gather_latin(nodeinv, edgeinv, elen, eidx, e0, t, Ah, s_cut);
    gather_lnorm(featN0, eidx, e0, t, Ah);
    __syncthreads();
    lat0_mfma2(W2aT, W2bT, t, Ah, AhB, s_cut);
    f32x4 acc0[4], acc1[4];
    mfma_gemm2<6>(8, Ah, AST, Wenv0aT, t, acc0, acc1);
#pragma unroll
    for (int i = 0; i < 2; ++i) {
        int nt = wave + 4 * i;
        if (nt < 6) {
#pragma unroll
            for (int i2 = 0; i2 < 4; ++i2) {
                s_w0h[(g * 4 + i2) * 96 + nt * 16 + r] = (_Float16)acc0[i][i2];
                s_w0h[(16 + g * 4 + i2) * 96 + nt * 16 + r] = (_Float16)acc1[i][i2];
            }
        }
    }
    mfma_gemm2<16>(11, Ah, AST, Wl1aT, t, acc0, acc1);
#pragma unroll
    for (int i = 0; i < 4; ++i) {
        int nt = wave + 4 * i;
#pragma unroll
        for (int i2 = 0; i2 < 4; ++i2) {
            AhB[(g * 4 + i2) * BST + nt * 16 + r] = (_Float16)silu(acc0[i][i2]);
            AhB[(16 + g * 4 + i2) * BST + nt * 16 + r] = (_Float16)silu(acc1[i][i2]);
        }
    }
    __syncthreads();
    mfma_gemm2<16>(8, AhB, BST, Wl1bT, t, acc0, acc1);
#pragma unroll
    for (int i = 0; i < 4; ++i) {
        int nt = wave + 4 * i;
#pragma unroll
        for (int i2 = 0; i2 < 4; ++i2) {
            int ro = g * 4 + i2, col = nt * 16 + r;
            float v0 = 0.8944271909999159f * (float)Ah[ro * AST + col] +
                       0.4472135954999579f * s_cut[ro] * silu(acc0[i][i2]);
            Ah[ro * AST + col] = (_Float16)v0;
            float v1 = 0.8944271909999159f * (float)Ah[(16 + ro) * AST + col] +
                       0.4472135954999579f * s_cut[16 + ro] * silu(acc1[i][i2]);
            Ah[(16 + ro) * AST + col] = (_Float16)v1;
        }
    }
    __syncthreads();
    for (int i = t; i < EB * 96; i += 256) {
        int ee = i / 96, rem = i - ee * 96;
        int l = rem >> 5, kk = rem & 31;
        int off = (l == 0) ? 0 : ((l == 1) ? 1 : 4);
        int d = (l == 0) ? 1 : ((l == 1) ? 3 : 5);
        int e = e0 + ee;
        const float* f = featN1 + (size_t)eidx[e] * 288 + kk;
        float s = 0.f;
        for (int mm = off; mm < off + d; ++mm)
            s = fmaf(f[mm * 32], edge_attr[(size_t)e * 9 + mm], s);
        s_S[ee * 96 + rem] = s;
    }
    __syncthreads();
    {
        int n15 = lane & 15, g8 = lane >> 4, mb = g8 * 4;
        f16x8 a0[8], a1[8];
#pragma unroll
        for (int cc = 0; cc < 8; ++cc) {
            a0[cc] = *(const f16x8*)(Ah + n15 * AST + cc * 32 + g8 * 8);
            a1[cc] = *(const f16x8*)(Ah + (16 + n15) * AST + cc * 32 + g8 * 8);
        }
        int ncombo = (wave < 2) ? 2 : 1;
        for (int ci = 0; ci < ncombo; ++ci) {
            int combo = wave + ci * 4;
            int l = combo >> 1, j0 = (combo & 1) * 16;
            f32x4 run0 = {0.f, 0.f, 0.f, 0.f}, run1 = {0.f, 0.f, 0.f, 0.f};
            for (int ke = 0; ke < 32; ++ke) {
                const _Float16* bb = Bfin + (size_t)(combo * 32 + ke) * 4096 + lane * 8;
                f32x4 ac0 = {0.f, 0.f, 0.f, 0.f}, ac1 = {0.f, 0.f, 0.f, 0.f};
#pragma unroll
                for (int cc = 0; cc < 8; ++cc) {
                    f16x8 b = *(const f16x8*)(bb + cc * 512);
                    ac0 = __builtin_amdgcn_mfma_f32_16x16x32_f16(a0[cc], b, ac0, 0, 0, 0);
                    ac1 = __builtin_amdgcn_mfma_f32_16x16x32_f16(a1[cc], b, ac1, 0, 0, 0);
                }
#pragma unroll
                for (int i2 = 0; i2 < 4; ++i2) {
                    run0[i2] = fmaf(ac0[i2], s_S[(mb + i2) * 96 + l * 32 + ke], run0[i2]);
                    run1[i2] = fmaf(ac1[i2], s_S[(16 + mb + i2) * 96 + l * 32 + ke], run1[i2]);
                }
            }
#pragma unroll
            for (int i2 = 0; i2 < 4; ++i2) {
                int jo = j0 + n15;
                Ah[(mb + i2) * AST + 256 + l * 32 + jo] =
                    (_Float16)((float)s_w0h[(mb + i2) * 96 + jo * 3 + l] * run0[i2]);
                Ah[(16 + mb + i2) * AST + 256 + l * 32 + jo] =
                    (_Float16)((float)s_w0h[(16 + mb + i2) * 96 + jo * 3 + l] * run1[i2]);
            }
        }
    }
    __syncthreads();
    mfma_gemm2<16>(11, Ah, AST, Wro1T, t, acc0, acc1);
    float v0[4] = {0.f, 0.f, 0.f, 0.f}, v1[4] = {0.f, 0.f, 0.f, 0.f};
#pragma unroll
    for (int i = 0; i < 4; ++i) {
        int col = (wave + 4 * i) * 16 + r;
        float w2 = Wro2[col];
#pragma unroll
        for (int i2 = 0; i2 < 4; ++i2) {
            v0[i2] += silu(acc0[i][i2]) * w2;
            v1[i2] += silu(acc1[i][i2]) * w2;
        }
    }
#pragma unroll
    for (int off = 1; off < 16; off <<= 1) {
#pragma unroll
        for (int i2 = 0; i2 < 4; ++i2) {
            v0[i2] += __shfl_xor(v0[i2], off);
            v1[i2] += __shfl_xor(v1[i2], off);
        }
    }
    if (r == 0) {
#pragma unroll
        for (int i2 = 0; i2 < 4; ++i2) {
            s_ps[g * 4 + i2][wave] = v0[i2];
            s_ps[16 + g * 4 + i2][wave] = v1[i2];
        }
    }
    __syncthreads();
    if (t < EB) out[e0 + t] = s_ps[t][0] + s_ps[t][1] + s_ps[t][2] + s_ps[t][3];
}

// ---------------------------------------------------------------- K5 fast v3: S-folded GEMM, 32x32x16, LDS dbuf pipeline
#define FEB 64
__global__ __launch_bounds__(512) void k5_fast(
    const float* __restrict__ edge_attr, const int* __restrict__ eidx,
    const _Float16* __restrict__ lat1h, const _Float16* __restrict__ w0h,
    const _Float16* __restrict__ BfinV3, const _Float16* __restrict__ Wro1T,
    const float* __restrict__ Wro2, const float* __restrict__ featN1,
    float* __restrict__ out) {
    __shared__ alignas(16) _Float16 Bst[2][8192];    // 32 KB (stage dbuf; overlaid by scal32 later)
    __shared__ alignas(16) _Float16 s_S[FEB * SST];  // 12.25 KB
    __shared__ alignas(16) _Float16 s_scalh[FEB * 96]; // 12 KB
    __shared__ float s_ps[FEB][4];
    float* s_scal32 = (float*)&Bst[0][0];            // 24 KB overlay (Bst dead)
    int t = threadIdx.x;
    int e0 = blockIdx.x * FEB;
    int wave = t >> 6, lane = t & 63;
    int r31 = lane & 31, kh5 = lane >> 5;
    int mt = wave >> 2, kq = wave & 3;   // contraction roles: 2 m-tiles x 4 K-quarters
    // ---- S gather: S[e, l*32+k] = sum_m featN1[center,m,k]*sh[e,m]
    for (int i = t; i < FEB * 96; i += 512) {
        int ee = i / 96, rem = i - ee * 96;
        int l = rem >> 5, kk = rem & 31;
        int off = (l == 0) ? 0 : ((l == 1) ? 1 : 4);
        int d = (l == 0) ? 1 : ((l == 1) ? 3 : 5);
        int e = e0 + ee;
        const float* f = featN1 + (size_t)eidx[e] * 288 + kk;
        float s = 0.f;
        for (int mm = off; mm < off + d; ++mm)
            s = fmaf(f[mm * 32], edge_attr[(size_t)e * 9 + mm], s);
        s_S[ee * SST + rem] = (_Float16)s;
    }
    // ---- A-frags (32x32 layout): row = lane&31, k = (lane>>5)*8+j
    f16x8 a2[4];
#pragma unroll
    for (int q = 0; q < 4; ++q)
        a2[q] = *(const f16x8*)(lat1h + (size_t)(e0 + mt * 32 + r31) * 256 +
                                (kq * 4 + q) * 16 + kh5 * 8);
    // ---- prologue: stage 0 into Bst[0] (reg-staged; 32B/thread)
    {
        const _Float16* g = BfinV3 + (size_t)t * 16;
        f16x8 g0 = *(const f16x8*)g, g1 = *(const f16x8*)(g + 8);
        *(f16x8*)&Bst[0][t * 16] = g0;
        *(f16x8*)&Bst[0][t * 16 + 8] = g1;
    }
    __syncthreads();
    const f32x16 z16 = {0.f, 0.f, 0.f, 0.f, 0.f, 0.f, 0.f, 0.f,
                        0.f, 0.f, 0.f, 0.f, 0.f, 0.f, 0.f, 0.f};
    f32x16 D[3];
    int cur = 0;
#pragma unroll
    for (int l = 0; l < 3; ++l) {
        D[l] = z16;
#pragma unroll 1
        for (int ke = 0; ke < 32; ++ke) {
            int s = l * 32 + ke;
            f16x8 g0, g1;
            if (s < 95) {  // issue next-stage loads early (T14)
                const _Float16* g = BfinV3 + (size_t)(s + 1) * 8192 + t * 16;
                g0 = *(const f16x8*)g;
                g1 = *(const f16x8*)(g + 8);
            }
            _Float16 sh = s_S[(mt * 32 + r31) * SST + l * 32 + ke];
            f16x8 sb = {sh, sh, sh, sh, sh, sh, sh, sh};
#pragma unroll
            for (int q = 0; q < 4; ++q) {
                f16x8 b = *(const f16x8*)&Bst[cur][(kq * 4 + q) * 512 + lane * 8];
                f16x8 ap = a2[q] * sb;   // fold S into A (v_pk_mul_f16)
                D[l] = __builtin_amdgcn_mfma_f32_32x32x16_f16(ap, b, D[l], 0, 0, 0);
            }
            __syncthreads();             // all reads of Bst[cur] done
            if (s < 95) {
                *(f16x8*)&Bst[cur ^ 1][t * 16] = g0;
                *(f16x8*)&Bst[cur ^ 1][t * 16 + 8] = g1;
            }
            __syncthreads();             // stage s+1 visible
            cur ^= 1;
        }
    }
    // ---- reduce 4 K-quarter partials via LDS f32 atomics (Bst dead -> scal32 overlay)
    for (int i = t; i < FEB * 96; i += 512) s_scal32[i] = 0.f;
    __syncthreads();
#pragma unroll
    for (int l = 0; l < 3; ++l) {
#pragma unroll
        for (int reg = 0; reg < 16; ++reg) {
            int row = (reg & 3) + 8 * (reg >> 2) + 4 * kh5;  // D layout (m74/m101)
            atomicAdd(&s_scal32[(mt * 32 + row) * 96 + l * 32 + r31], D[l][reg]);
        }
    }
    __syncthreads();
    // ---- apply w0 -> scal f16
    for (int i = t; i < FEB * 96; i += 512) {
        int m = i / 96, rem = i - m * 96;
        int l = rem >> 5, jo = rem & 31;
        float w0 = (float)w0h[(size_t)(e0 + m) * 96 + jo * 3 + l];
        s_scalh[i] = (_Float16)(s_scal32[i] * w0);
    }
    __syncthreads();
    // ---- readout (R8 structure): A cols 0..255 from lat1h, 256..351 from s_scalh
    int r = lane & 15, g8 = lane >> 4;
    int mh = wave >> 2, w4 = wave & 3;
    int eh = e0 + mh * 32;
    f16x8 a[2][8];
#pragma unroll
    for (int mt2 = 0; mt2 < 2; ++mt2)
#pragma unroll
        for (int cc = 0; cc < 8; ++cc)
            a[mt2][cc] = *(const f16x8*)(lat1h + (size_t)(eh + mt2 * 16 + r) * 256 +
                                         cc * 32 + g8 * 8);
    f32x4 racc[4][2];
#pragma unroll
    for (int i = 0; i < 4; ++i)
#pragma unroll
        for (int mt2 = 0; mt2 < 2; ++mt2) racc[i][mt2] = (f32x4){0.f, 0.f, 0.f, 0.f};
#pragma unroll
    for (int ks = 0; ks < 11; ++ks) {
        f16x8 af0 = (ks < 8) ? a[0][ks]
                             : *(const f16x8*)(s_scalh + (mh * 32 + r) * 96 + (ks - 8) * 32 + g8 * 8);
        f16x8 af1 = (ks < 8) ? a[1][ks]
                             : *(const f16x8*)(s_scalh + (mh * 32 + 16 + r) * 96 + (ks - 8) * 32 + g8 * 8);
#pragma unroll
        for (int i = 0; i < 4; ++i) {
            int nt = w4 + 4 * i;
            f16x8 b = *(const f16x8*)(Wro1T + ((size_t)(nt * 11 + ks) * 64 + lane) * 8);
            racc[i][0] = __builtin_amdgcn_mfma_f32_16x16x32_f16(af0, b, racc[i][0], 0, 0, 0);
            racc[i][1] = __builtin_amdgcn_mfma_f32_16x16x32_f16(af1, b, racc[i][1], 0, 0, 0);
        }
    }
    float v[2][4];
#pragma unroll
    for (int mt2 = 0; mt2 < 2; ++mt2)
#pragma unroll
        for (int i2 = 0; i2 < 4; ++i2) v[mt2][i2] = 0.f;
#pragma unroll
    for (int i = 0; i < 4; ++i) {
        int col = (w4 + 4 * i) * 16 + r;
        float w2 = Wro2[col];
#pragma unroll
        for (int mt2 = 0; mt2 < 2; ++mt2)
#pragma unroll
            for (int i2 = 0; i2 < 4; ++i2) v[mt2][i2] += silu(racc[i][mt2][i2]) * w2;
    }
#pragma unroll
    for (int off = 1; off < 16; off <<= 1)
#pragma unroll
        for (int mt2 = 0; mt2 < 2; ++mt2)
#pragma unroll
            for (int i2 = 0; i2 < 4; ++i2) v[mt2][i2] += __shfl_xor(v[mt2][i2], off);
    if (r == 0) {
#pragma unroll
        for (int mt2 = 0; mt2 < 2; ++mt2)
#pragma unroll
            for (int i2 = 0; i2 < 4; ++i2)
                s_ps[mh * 32 + mt2 * 16 + g8 * 4 + i2][w4] = v[mt2][i2];
    }
    __syncthreads();
    if (t < FEB) out[e0 + t] = s_ps[t][0] + s_ps[t][1] + s_ps[t][2] + s_ps[t][3];
}

// ----------------------------------------------------------------
extern "C" void kernel_launch(void* const* d_in, const int* in_sizes, int n_in,
                              void* d_out, int out_size, void* d_ws, size_t ws_size,
                              hipStream_t stream) {
    (void)in_sizes; (void)n_in; (void)out_size;
    const float* edge_attr = (const float*)d_in[0];
    const float* edge_len  = (const float*)d_in[1];
    const float* edge_inv  = (const float*)d_in[2];
    const float* node_inv  = (const float*)d_in[3];
    const float* W2a     = (const float*)d_in[4];
    const float* W2b     = (const float*)d_in[5];
    const float* Wl1a    = (const float*)d_in[6];
    const float* Wl1b    = (const float*)d_in[7];
    const float* Wenv0   = (const float*)d_in[8];
    const float* Wenv1   = (const float*)d_in[9];
    const float* Wenvlin = (const float*)d_in[10];
    const float* Wprod   = (const float*)d_in[11];
    const float* Wfeat   = (const float*)d_in[12];
    const float* Wfinlat = (const float*)d_in[13];
    const float* Wro1    = (const float*)d_in[14];
    const float* Wro2    = (const float*)d_in[15];
    const int* eidx      = (const int*)d_in[16];
    float* out = (float*)d_out;

    _Float16* p = (_Float16*)d_ws;
    _Float16* Bfin    = p; p += 786432;
    _Float16* BfinV3  = p; p += 786432;
    _Float16* W2aT    = p; p += 40960;
    _Float16* W2bT    = p; p += 65536;
    _Float16* Wenv0aT = p; p += 24576;
    _Float16* Wenv0bT = p; p += 24576;
    _Float16* Wenv1T  = p; p += 24576;
    _Float16* Wl1aT   = p; p += 90112;
    _Float16* Wl1bT   = p; p += 65536;
    _Float16* Wro1T   = p; p += 90112;
    float* env    = (float*)p;
    float* featN0 = env + (size_t)NNODES * 288;
    char* after = (char*)(featN0 + (size_t)NNODES * 288);
    size_t need_slow = (size_t)(after - (char*)d_ws);
    if (ws_size < need_slow) return;
    _Float16* lat1h = (_Float16*)after;                       // NE*256 f16
    _Float16* w0h   = lat1h + (size_t)NE * 256;               // NE*96 f16
    size_t need_fast = need_slow + (size_t)NE * (256 + 96) * sizeof(_Float16);
    bool fast = (ws_size >= need_fast);
    if (!fast) { lat1h = nullptr; w0h = nullptr; }

    const int ENV_N = NNODES * 288;
    k_packfin<<<3072, 256, 0, stream>>>(Wfinlat, Bfin);
    k_packfin3<<<3072, 256, 0, stream>>>(Wfinlat, BfinV3);
    k_packf<<<160, 256, 0, stream>>>(W2a, W2aT, 136, 5, 16, 256, 0);
    k_packf<<<256, 256, 0, stream>>>(W2b, W2bT, 256, 8, 16, 256, 0);
    k_packf<<<96, 256, 0, stream>>>(Wenv0, Wenv0aT, 256, 8, 6, 192, 0);
    k_packf<<<96, 256, 0, stream>>>(Wenv0, Wenv0bT, 256, 8, 6, 192, 96);
    k_packf<<<96, 256, 0, stream>>>(Wenv1, Wenv1T, 256, 8, 6, 96, 0);
    k_packf<<<352, 256, 0, stream>>>(Wl1a, Wl1aT, 352, 11, 16, 256, 0);
    k_packf<<<256, 256, 0, stream>>>(Wl1b, Wl1bT, 256, 8, 16, 256, 0);
    k_packf<<<352, 256, 0, stream>>>(Wro1, Wro1T, 352, 11, 16, 256, 0);

    k_zero<<<(ENV_N + 255) / 256, 256, 0, stream>>>(env, ENV_N);
    k1_lat_scatter0<<<NBLK, 256, 0, stream>>>(node_inv, edge_inv, edge_len, edge_attr,
                                              eidx, W2aT, W2bT, Wenv0bT, env);
    k_node<<<NNODES, 288, 0, stream>>>(env, node_inv, Wenvlin, Wprod, Wfeat, featN0);
    k_zero<<<(ENV_N + 255) / 256, 256, 0, stream>>>(env, ENV_N);
    k3_update_scatter1<<<NBLK, 256, 0, stream>>>(node_inv, edge_inv, edge_len, edge_attr,
                                                 eidx, W2aT, W2bT, Wl1aT, Wl1bT, Wenv1T,
                                                 Wenv0aT, featN0, env, lat1h, w0h);
    k_node<<<NNODES, 288, 0, stream>>>(env, node_inv, Wenvlin + 3072, Wprod + 6144,
                                       Wfeat + 3072, env);  // in-place: env1 -> featN1
    if (fast) {
        k5_fast<<<NE / FEB, 512, 0, stream>>>(edge_attr, eidx, lat1h, w0h, BfinV3, Wro1T,
                                              Wro2, env, out);
    } else {
        k5_final<<<NBLK, 256, 0, stream>>>(node_inv, edge_inv, edge_len, edge_attr, eidx,
                                           W2aT, W2bT, Wenv0aT, Wl1aT, Wl1bT, Bfin, Wro1T,
                                           Wro2, featN0, env, out);
    }
}

// Round 10
// 3813.096 us; speedup vs baseline: 1.3213x; 1.2345x over previous
//
#include <hip/hip_runtime.h>
#include <math.h>

#define NE 320000
#define NNODES 10000
#define EB 32
#define NBLK (NE / EB)
#define AST 360   // Ah stride (f16 elems)
#define BST 264   // AhB stride (f16 elems)
#define SST 98    // padded S/scal stride (f16)

typedef _Float16 f16x8 __attribute__((ext_vector_type(8)));
typedef float f32x4 __attribute__((ext_vector_type(4)));

__device__ __forceinline__ float silu(float x) { return x / (1.0f + __expf(-x)); }
__device__ __forceinline__ float cutf(float len) {
    float x = len * (1.0f / 6.0f);
    float x2 = x * x, x6 = x2 * x2 * x2;
    float f = 1.0f - 28.0f * x6 + 48.0f * x6 * x - 21.0f * x6 * x2;
    return (x < 1.0f) ? f : 0.0f;
}

// ---------------------------------------------------------------- zero
__global__ __launch_bounds__(256) void k_zero(float* __restrict__ p, int n) {
    int i = blockIdx.x * 256 + threadIdx.x;
    if (i < n) p[i] = 0.f;
}

// ---------------------------------------------------------------- fragment-major pack for MLP weights
__global__ __launch_bounds__(256) void k_packf(const float* __restrict__ src,
                                               _Float16* __restrict__ dst,
                                               int K, int KS, int NT, int stride,
                                               int colOff) {
    int i = blockIdx.x * 256 + threadIdx.x;
    if (i >= NT * KS * 512) return;
    int j = i & 7, lane = (i >> 3) & 63;
    int blk = i >> 9;
    int ks = blk % KS, nt = blk / KS;
    int k = ks * 32 + (lane >> 4) * 8 + j;
    int n = colOff + nt * 16 + (lane & 15);
    dst[i] = (k < K) ? (_Float16)src[(size_t)k * stride + n] : (_Float16)0.f;
}

// ---------------------------------------------------------------- old fragment-major pack of Wfinlat (fallback path)
__global__ __launch_bounds__(256) void k_packfin(const float* __restrict__ W,
                                                 _Float16* __restrict__ dst) {
    int i = blockIdx.x * 256 + threadIdx.x;  // < 786432
    int j = i & 7, lane = (i >> 3) & 63, cc = (i >> 9) & 7, ke = (i >> 12) & 31,
        combo = i >> 17;
    int n = (combo >> 1) * 1024 + ke * 32 + (combo & 1) * 16 + (lane & 15);
    int c = cc * 32 + (lane >> 4) * 8 + j;
    dst[i] = (_Float16)W[(size_t)c * 3072 + n];
}

// ---------------------------------------------------------------- stage-major pack of Wfinlat for 16x16x32 pipeline
// stage s = l*32+ke; within stage: unit u = nt*8+cc (16 units of 512 f16):
// dst[s*8192 + u*512 + lane*8 + j] = Wfin[c = cc*32+(lane>>4)*8+j][l*1024+ke*32+nt*16+(lane&15)]
__global__ __launch_bounds__(256) void k_packfin4(const float* __restrict__ W,
                                                  _Float16* __restrict__ dst) {
    int i = blockIdx.x * 256 + threadIdx.x;  // < 786432
    int j = i & 7, lane = (i >> 3) & 63, u = (i >> 9) & 15, s = i >> 13;
    int nt = u >> 3, cc = u & 7;
    int l = s >> 5, ke = s & 31;
    int c = cc * 32 + ((lane >> 4) & 3) * 8 + j;
    int n = l * 1024 + ke * 32 + nt * 16 + (lane & 15);
    dst[i] = (_Float16)W[(size_t)c * 3072 + n];
}

// ---------------------------------------------------------------- MFMA GEMM, 32 edges (2 m-tiles), frag-major B
template <int NT>
__device__ __forceinline__ void mfma_gemm2(int ksteps, const _Float16* Ah, int astride,
                                           const _Float16* __restrict__ Wt, int t,
                                           f32x4* acc0, f32x4* acc1) {
    int wave = t >> 6, lane = t & 63, r = lane & 15, g = lane >> 4;
    const int TPW = (NT + 3) / 4;
#pragma unroll
    for (int i = 0; i < TPW; ++i) {
        acc0[i] = (f32x4){0.f, 0.f, 0.f, 0.f};
        acc1[i] = (f32x4){0.f, 0.f, 0.f, 0.f};
    }
    for (int ks = 0; ks < ksteps; ++ks) {
        f16x8 a0 = *(const f16x8*)(Ah + r * astride + ks * 32 + g * 8);
        f16x8 a1 = *(const f16x8*)(Ah + (16 + r) * astride + ks * 32 + g * 8);
#pragma unroll
        for (int i = 0; i < TPW; ++i) {
            int nt = wave + 4 * i;
            if (nt < NT) {
                f16x8 b = *(const f16x8*)(Wt + ((size_t)(nt * ksteps + ks) * 64 + lane) * 8);
                acc0[i] = __builtin_amdgcn_mfma_f32_16x16x32_f16(a0, b, acc0[i], 0, 0, 0);
                acc1[i] = __builtin_amdgcn_mfma_f32_16x16x32_f16(a1, b, acc1[i], 0, 0, 0);
            }
        }
    }
}

// gather lat_in -> Ah cols 0..159 (f16), compute s_cut
__device__ __forceinline__ void gather_latin(
    const float* __restrict__ nodeinv, const float* __restrict__ edgeinv,
    const float* __restrict__ elen, const int* __restrict__ eidx,
    int e0, int t, _Float16* Ah, float* s_cut) {
    if (t < EB) s_cut[t] = cutf(elen[e0 + t]);
    for (int i = t; i < EB * 160; i += 256) {
        int ee = i / 160, k = i - ee * 160;
        int e = e0 + ee;
        float v;
        if (k < 64)       v = nodeinv[eidx[e] * 64 + k];
        else if (k < 128) v = nodeinv[eidx[NE + e] * 64 + (k - 64)];
        else if (k < 136) v = edgeinv[(size_t)e * 8 + (k - 128)];
        else              v = 0.f;
        Ah[ee * AST + k] = (_Float16)v;
    }
}

// lat0 (2 GEMMs) -> Ah cols 0..255 f16
__device__ __forceinline__ void lat0_mfma2(const _Float16* __restrict__ W2aT,
                                           const _Float16* __restrict__ W2bT,
                                           int t, _Float16* Ah, _Float16* AhB,
                                           const float* s_cut) {
    int wave = t >> 6, lane = t & 63, r = lane & 15, g = lane >> 4;
    f32x4 acc0[4], acc1[4];
    mfma_gemm2<16>(5, Ah, AST, W2aT, t, acc0, acc1);
#pragma unroll
    for (int i = 0; i < 4; ++i) {
        int nt = wave + 4 * i;
#pragma unroll
        for (int i2 = 0; i2 < 4; ++i2) {
            AhB[(g * 4 + i2) * BST + nt * 16 + r] = (_Float16)silu(acc0[i][i2]);
            AhB[(16 + g * 4 + i2) * BST + nt * 16 + r] = (_Float16)silu(acc1[i][i2]);
        }
    }
    __syncthreads();
    mfma_gemm2<16>(8, AhB, BST, W2bT, t, acc0, acc1);
#pragma unroll
    for (int i = 0; i < 4; ++i) {
        int nt = wave + 4 * i;
#pragma unroll
        for (int i2 = 0; i2 < 4; ++i2) {
            int ro = g * 4 + i2, col = nt * 16 + r;
            Ah[ro * AST + col] = (_Float16)(s_cut[ro] * silu(acc0[i][i2]));
            Ah[(16 + ro) * AST + col] = (_Float16)(s_cut[16 + ro] * silu(acc1[i][i2]));
        }
    }
    __syncthreads();
}

// lnorm(featN[center]) -> Ah cols 256..351 f16
__device__ __forceinline__ void gather_lnorm(const float* __restrict__ featN,
                                             const int* __restrict__ eidx,
                                             int e0, int t, _Float16* Ah) {
    for (int i = t; i < EB * 96; i += 256) {
        int ee = i / 96, rem = i - ee * 96;
        int l = rem >> 5, kk = rem & 31;
        int off = (l == 0) ? 0 : ((l == 1) ? 1 : 4);
        int d = (l == 0) ? 1 : ((l == 1) ? 3 : 5);
        const float* f = featN + (size_t)eidx[e0 + ee] * 288 + kk;
        float s = 1e-8f;
        for (int mm = off; mm < off + d; ++mm) { float x = f[mm * 32]; s = fmaf(x, x, s); }
        Ah[ee * AST + 256 + rem] = (_Float16)sqrtf(s);
    }
}

// scatter env += weight_channels(sh, s_w)*cut  (s_w f32 [EB][96])
__device__ __forceinline__ void scatter_env(const float* __restrict__ edge_attr,
                                            const int* __restrict__ eidx,
                                            const float* s_w, const float* s_cut,
                                            int e0, int t, float* __restrict__ env) {
    for (int i = t; i < EB * 32; i += 256) {
        int el = i >> 5, k = i & 31;
        int e = e0 + el;
        float cw = s_cut[el];
        int n = eidx[e];
        float w0 = s_w[el * 96 + k * 3 + 0] * cw;
        float w1 = s_w[el * 96 + k * 3 + 1] * cw;
        float w2 = s_w[el * 96 + k * 3 + 2] * cw;
        float* dst = env + (size_t)n * 288 + k;
#pragma unroll
        for (int m = 0; m < 9; ++m) {
            float w = (m == 0) ? w0 : ((m < 4) ? w1 : w2);
            atomicAdd(dst + m * 32, edge_attr[(size_t)e * 9 + m] * w);
        }
    }
}

// NT=6 epilogue -> s_w (f32)
__device__ __forceinline__ void epi6_f32(const f32x4* acc0, const f32x4* acc1, int t,
                                         float* s_w) {
    int wave = t >> 6, lane = t & 63, r = lane & 15, g = lane >> 4;
#pragma unroll
    for (int i = 0; i < 2; ++i) {
        int nt = wave + 4 * i;
        if (nt < 6) {
#pragma unroll
            for (int i2 = 0; i2 < 4; ++i2) {
                s_w[(g * 4 + i2) * 96 + nt * 16 + r] = acc0[i][i2];
                s_w[(16 + g * 4 + i2) * 96 + nt * 16 + r] = acc1[i][i2];
            }
        }
    }
}

// ---------------------------------------------------------------- K1: lat0 + (lat0@Wenv0b) + scatter
__global__ __launch_bounds__(256) void k1_lat_scatter0(
    const float* __restrict__ nodeinv, const float* __restrict__ edgeinv,
    const float* __restrict__ elen, const float* __restrict__ edge_attr,
    const int* __restrict__ eidx, const _Float16* __restrict__ W2aT,
    const _Float16* __restrict__ W2bT, const _Float16* __restrict__ Wenv0bT,
    float* __restrict__ env) {
    __shared__ alignas(16) _Float16 Ah[EB * AST];
    __shared__ alignas(16) _Float16 AhB[EB * BST];
    __shared__ float s_cut[EB];
    float* s_w = (float*)AhB;  // overlay: AhB dead after lat0
    int t = threadIdx.x;
    int e0 = blockIdx.x * EB;
    gather_latin(nodeinv, edgeinv, elen, eidx, e0, t, Ah, s_cut);
    __syncthreads();
    lat0_mfma2(W2aT, W2bT, t, Ah, AhB, s_cut);
    f32x4 acc0[4], acc1[4];
    mfma_gemm2<6>(8, Ah, AST, Wenv0bT, t, acc0, acc1);
    epi6_f32(acc0, acc1, t, s_w);
    __syncthreads();
    scatter_env(edge_attr, eidx, s_w, s_cut, e0, t, env);
}

// ---------------------------------------------------------------- node transform (unchanged)
__global__ __launch_bounds__(288) void k_node(
    const float* envin, const float* __restrict__ nodeinv,
    const float* __restrict__ Wenvlin, const float* __restrict__ Wprod,
    const float* __restrict__ Wfeat, float* featOut) {
    __shared__ float s_env[288];
    __shared__ float s_inv[64];
    __shared__ float s_mix[288];
    __shared__ float s_ew[96];
    int n = blockIdx.x;
    int t = threadIdx.x;
    s_env[t] = envin[(size_t)n * 288 + t] * (1.0f / 32.0f);
    if (t < 64) s_inv[t] = nodeinv[n * 64 + t];
    __syncthreads();
    int m = t >> 5, j = t & 31;
    int l = (m == 0) ? 0 : ((m < 4) ? 1 : 2);
    float a = 0.f;
    for (int k = 0; k < 32; ++k) a = fmaf(s_env[m * 32 + k], Wenvlin[l * 1024 + k * 32 + j], a);
    if (t < 96) {
        int c = t >> 5, jj = t & 31;
        float b = 0.f;
        for (int tt = 0; tt < 64; ++tt) b = fmaf(s_inv[tt], Wprod[c * 2048 + tt * 32 + jj], b);
        s_ew[t] = b;
    }
    s_mix[t] = a;
    __syncthreads();
    float s = s_mix[j];
    float p = s_mix[t] * (s_ew[j] + s_ew[32 + j] * s + s_ew[64 + j] * s * s);
    __syncthreads();
    s_env[t] = p;
    __syncthreads();
    float o = 0.f;
    for (int jl = 0; jl < 32; ++jl) o = fmaf(s_env[m * 32 + jl], Wfeat[l * 1024 + jl * 32 + j], o);
    featOut[(size_t)n * 288 + t] = o;
}

// ---------------------------------------------------------------- K3: lat0 -> lat1 -> (lat1@Wenv1) + scatter [+ persist lat1h,w0h]
__global__ __launch_bounds__(256) void k3_update_scatter1(
    const float* __restrict__ nodeinv, const float* __restrict__ edgeinv,
    const float* __restrict__ elen, const float* __restrict__ edge_attr,
    const int* __restrict__ eidx, const _Float16* __restrict__ W2aT,
    const _Float16* __restrict__ W2bT, const _Float16* __restrict__ Wl1aT,
    const _Float16* __restrict__ Wl1bT, const _Float16* __restrict__ Wenv1T,
    const _Float16* __restrict__ Wenv0aT, const float* __restrict__ featN0,
    float* __restrict__ env, _Float16* __restrict__ lat1h,
    _Float16* __restrict__ w0h) {
    __shared__ alignas(16) _Float16 Ah[EB * AST];
    __shared__ alignas(16) _Float16 AhB[EB * BST];
    __shared__ float s_cut[EB];
    float* s_w = (float*)AhB;
    int t = threadIdx.x;
    int e0 = blockIdx.x * EB;
    int wave = t >> 6, lane = t & 63, r = lane & 15, g = lane >> 4;
    gather_latin(nodeinv, edgeinv, elen, eidx, e0, t, Ah, s_cut);
    gather_lnorm(featN0, eidx, e0, t, Ah);
    __syncthreads();
    lat0_mfma2(W2aT, W2bT, t, Ah, AhB, s_cut);
    f32x4 acc0[4], acc1[4];
    if (w0h) {  // w0 = lat0 @ Wenv0[:,0:96] (lat0 still in Ah)
        mfma_gemm2<6>(8, Ah, AST, Wenv0aT, t, acc0, acc1);
#pragma unroll
        for (int i = 0; i < 2; ++i) {
            int nt = wave + 4 * i;
            if (nt < 6) {
#pragma unroll
                for (int i2 = 0; i2 < 4; ++i2) {
                    w0h[(size_t)(e0 + g * 4 + i2) * 96 + nt * 16 + r] = (_Float16)acc0[i][i2];
                    w0h[(size_t)(e0 + 16 + g * 4 + i2) * 96 + nt * 16 + r] = (_Float16)acc1[i][i2];
                }
            }
        }
    }
    mfma_gemm2<16>(11, Ah, AST, Wl1aT, t, acc0, acc1);
#pragma unroll
    for (int i = 0; i < 4; ++i) {
        int nt = wave + 4 * i;
#pragma unroll
        for (int i2 = 0; i2 < 4; ++i2) {
            AhB[(g * 4 + i2) * BST + nt * 16 + r] = (_Float16)silu(acc0[i][i2]);
            AhB[(16 + g * 4 + i2) * BST + nt * 16 + r] = (_Float16)silu(acc1[i][i2]);
        }
    }
    __syncthreads();
    mfma_gemm2<16>(8, AhB, BST, Wl1bT, t, acc0, acc1);
#pragma unroll
    for (int i = 0; i < 4; ++i) {
        int nt = wave + 4 * i;
#pragma unroll
        for (int i2 = 0; i2 < 4; ++i2) {
            int ro = g * 4 + i2, col = nt * 16 + r;
            float v0 = 0.8944271909999159f * (float)Ah[ro * AST + col] +
                       0.4472135954999579f * s_cut[ro] * silu(acc0[i][i2]);
            _Float16 h0 = (_Float16)v0;
            Ah[ro * AST + col] = h0;
            float v1 = 0.8944271909999159f * (float)Ah[(16 + ro) * AST + col] +
                       0.4472135954999579f * s_cut[16 + ro] * silu(acc1[i][i2]);
            _Float16 h1 = (_Float16)v1;
            Ah[(16 + ro) * AST + col] = h1;
            if (lat1h) {
                lat1h[(size_t)(e0 + ro) * 256 + col] = h0;
                lat1h[(size_t)(e0 + 16 + ro) * 256 + col] = h1;
            }
        }
    }
    __syncthreads();
    mfma_gemm2<6>(8, Ah, AST, Wenv1T, t, acc0, acc1);
    epi6_f32(acc0, acc1, t, s_w);
    __syncthreads();
    scatter_env(edge_attr, eidx, s_w, s_cut, e0, t, env);
}

// ---------------------------------------------------------------- K5 slow (fallback): recompute path (old Bfin layout)
__global__ __launch_bounds__(256) void k5_final(
    const float* __restrict__ nodeinv, const float* __restrict__ edgeinv,
    const float* __restrict__ elen, const float* __restrict__ edge_attr,
    const int* __restrict__ eidx, const _Float16* __restrict__ W2aT,
    const _Float16* __restrict__ W2bT, const _Float16* __restrict__ Wenv0aT,
    const _Float16* __restrict__ Wl1aT, const _Float16* __restrict__ Wl1bT,
    const _Float16* __restrict__ Bfin, const _Float16* __restrict__ Wro1T,
    const float* __restrict__ Wro2, const float* __restrict__ featN0,
    const float* __restrict__ featN1, float* __restrict__ out) {
    __shared__ alignas(16) _Float16 Ah[EB * AST];
    __shared__ alignas(16) _Float16 AhB[EB * BST];
    __shared__ alignas(16) _Float16 s_w0h[EB * 96];
    __shared__ float s_cut[EB];
    __shared__ float s_ps[EB][4];
    float* s_S = (float*)AhB;
    int t = threadIdx.x;
    int e0 = blockIdx.x * EB;
    int wave = t >> 6, lane = t & 63, r = lane & 15, g = lane >> 4;
    gather_latin(nodeinv, edgeinv, elen, eidx, e0, t, Ah, s_cut);
    gather_lnorm(featN0, eidx, e0, t, Ah);
    __syncthreads();
    lat0_mfma2(W2aT, W2bT, t, Ah, AhB, s_cut);
    f32x4 acc0[4], acc1[4];
    mfma_gemm2<6>(8, Ah, AST, Wenv0aT, t, acc0, acc1);
#pragma unroll
    for (int i = 0; i < 2; ++i) {
        int nt = wave + 4 * i;
        if (nt < 6) {
#pragma unroll
            for (int i2 = 0; i2 < 4; ++i2) {
                s_w0h[(g * 4 + i2) * 96 + nt * 16 + r] = (_Float16)acc0[i][i2];
                s_w0h[(16 + g * 4 + i2) * 96 + nt * 16 + r] = (_Float16)acc1[i][i2];
            }
        }
    }
    mfma_gemm2<16>(11, Ah, AST, Wl1aT, t, acc0, acc1);
#pragma unroll
    for (int i = 0; i < 4; ++i) {
        int nt = wave + 4 * i;
#pragma unroll
        for (int i2 = 0; i2 < 4; ++i2) {
            AhB[(g * 4 + i2) * BST + nt * 16 + r] = (_Float16)silu(acc0[i][i2]);
            AhB[(16 + g * 4 + i2) * BST + nt * 16 + r] = (_Float16)silu(acc1[i][i2]);
        }
    }
    __syncthreads();
    mfma_gemm2<16>(8, AhB, BST, Wl1bT, t, acc0, acc1);
#pragma unroll
    for (int i = 0; i < 4; ++i) {
        int nt = wave + 4 * i;
#pragma unroll
        for (int i2 = 0; i2 < 4; ++i2) {
            int ro = g * 4 + i2, col = nt * 16 + r;
            float v0 = 0.8944271909999159f * (float)Ah[ro * AST + col] +
                       0.4472135954999579f * s_cut[ro] * silu(acc0[i][i2]);
            Ah[ro * AST + col] = (_Float16)v0;
            float v1 = 0.8944271909999159f * (float)Ah[(16 + ro) * AST + col] +
                       0.4472135954999579f * s_cut[16 + ro] * silu(acc1[i][i2]);
            Ah[(16 + ro) * AST + col] = (_Float16)v1;
        }
    }
    __syncthreads();
    for (int i = t; i < EB * 96; i += 256) {
        int ee = i / 96, rem = i - ee * 96;
        int l = rem >> 5, kk = rem & 31;
        int off = (l == 0) ? 0 : ((l == 1) ? 1 : 4);
        int d = (l == 0) ? 1 : ((l == 1) ? 3 : 5);
        int e = e0 + ee;
        const float* f = featN1 + (size_t)eidx[e] * 288 + kk;
        float s = 0.f;
        for (int mm = off; mm < off + d; ++mm)
            s = fmaf(f[mm * 32], edge_attr[(size_t)e * 9 + mm], s);
        s_S[ee * 96 + rem] = s;
    }
    __syncthreads();
    {
        int n15 = lane & 15, g8 = lane >> 4, mb = g8 * 4;
        f16x8 a0[8], a1[8];
#pragma unroll
        for (int cc = 0; cc < 8; ++cc) {
            a0[cc] = *(const f16x8*)(Ah + n15 * AST + cc * 32 + g8 * 8);
            a1[cc] = *(const f16x8*)(Ah + (16 + n15) * AST + cc * 32 + g8 * 8);
        }
        int ncombo = (wave < 2) ? 2 : 1;
        for (int ci = 0; ci < ncombo; ++ci) {
            int combo = wave + ci * 4;
            int l = combo >> 1, j0 = (combo & 1) * 16;
            f32x4 run0 = {0.f, 0.f, 0.f, 0.f}, run1 = {0.f, 0.f, 0.f, 0.f};
            for (int ke = 0; ke < 32; ++ke) {
                const _Float16* bb = Bfin + (size_t)(combo * 32 + ke) * 4096 + lane * 8;
                f32x4 ac0 = {0.f, 0.f, 0.f, 0.f}, ac1 = {0.f, 0.f, 0.f, 0.f};
#pragma unroll
                for (int cc = 0; cc < 8; ++cc) {
                    f16x8 b = *(const f16x8*)(bb + cc * 512);
                    ac0 = __builtin_amdgcn_mfma_f32_16x16x32_f16(a0[cc], b, ac0, 0, 0, 0);
                    ac1 = __builtin_amdgcn_mfma_f32_16x16x32_f16(a1[cc], b, ac1, 0, 0, 0);
                }
#pragma unroll
                for (int i2 = 0; i2 < 4; ++i2) {
                    run0[i2] = fmaf(ac0[i2], s_S[(mb + i2) * 96 + l * 32 + ke], run0[i2]);
                    run1[i2] = fmaf(ac1[i2], s_S[(16 + mb + i2) * 96 + l * 32 + ke], run1[i2]);
                }
            }
#pragma unroll
            for (int i2 = 0; i2 < 4; ++i2) {
                int jo = j0 + n15;
                Ah[(mb + i2) * AST + 256 + l * 32 + jo] =
                    (_Float16)((float)s_w0h[(mb + i2) * 96 + jo * 3 + l] * run0[i2]);
                Ah[(16 + mb + i2) * AST + 256 + l * 32 + jo] =
                    (_Float16)((float)s_w0h[(16 + mb + i2) * 96 + jo * 3 + l] * run1[i2]);
            }
        }
    }
    __syncthreads();
    mfma_gemm2<16>(11, Ah, AST, Wro1T, t, acc0, acc1);
    float v0[4] = {0.f, 0.f, 0.f, 0.f}, v1[4] = {0.f, 0.f, 0.f, 0.f};
#pragma unroll
    for (int i = 0; i < 4; ++i) {
        int col = (wave + 4 * i) * 16 + r;
        float w2 = Wro2[col];
#pragma unroll
        for (int i2 = 0; i2 < 4; ++i2) {
            v0[i2] += silu(acc0[i][i2]) * w2;
            v1[i2] += silu(acc1[i][i2]) * w2;
        }
    }
#pragma unroll
    for (int off = 1; off < 16; off <<= 1) {
#pragma unroll
        for (int i2 = 0; i2 < 4; ++i2) {
            v0[i2] += __shfl_xor(v0[i2], off);
            v1[i2] += __shfl_xor(v1[i2], off);
        }
    }
    if (r == 0) {
#pragma unroll
        for (int i2 = 0; i2 < 4; ++i2) {
            s_ps[g * 4 + i2][wave] = v0[i2];
            s_ps[16 + g * 4 + i2][wave] = v1[i2];
        }
    }
    __syncthreads();
    if (t < EB) out[e0 + t] = s_ps[t][0] + s_ps[t][1] + s_ps[t][2] + s_ps[t][3];
}

// ---------------------------------------------------------------- K5 fast v4: FEB=128, full-K waves (16x16x32), no LDS atomics
#define FEB 128
__global__ __launch_bounds__(512) void k5_fast(
    const float* __restrict__ edge_attr, const int* __restrict__ eidx,
    const _Float16* __restrict__ lat1h, const _Float16* __restrict__ w0h,
    const _Float16* __restrict__ BfinV4, const _Float16* __restrict__ Wro1T,
    const float* __restrict__ Wro2, const float* __restrict__ featN1,
    float* __restrict__ out) {
    __shared__ alignas(16) _Float16 Bst[2][8192];   // 32 KB stage dbuf
    __shared__ alignas(16) _Float16 s_S[FEB * SST]; // 25 KB: S, then scal overlay
    __shared__ float s_ps[FEB][2];                  // 1 KB
    int t = threadIdx.x;
    int e0 = blockIdx.x * FEB;
    int wave = t >> 6, lane = t & 63;
    int r15 = lane & 15, g8 = lane >> 4;
    int erow = e0 + wave * 16 + r15;   // this lane's edge row (contraction)
    // ---- S gather: S[e, l*32+k] = sum_m featN1[center,m,k]*sh[e,m]
    for (int i = t; i < FEB * 96; i += 512) {
        int ee = i / 96, rem = i - ee * 96;
        int l = rem >> 5, kk = rem & 31;
        int off = (l == 0) ? 0 : ((l == 1) ? 1 : 4);
        int d = (l == 0) ? 1 : ((l == 1) ? 3 : 5);
        int e = e0 + ee;
        const float* f = featN1 + (size_t)eidx[e] * 288 + kk;
        float s = 0.f;
        for (int mm = off; mm < off + d; ++mm)
            s = fmaf(f[mm * 32], edge_attr[(size_t)e * 9 + mm], s);
        s_S[ee * SST + rem] = (_Float16)s;
    }
    // ---- A-frags (16x16x32): row = lane&15, k = g8*8+j; a2[cc] covers c = cc*32
    f16x8 a2[8];
#pragma unroll
    for (int cc = 0; cc < 8; ++cc)
        a2[cc] = *(const f16x8*)(lat1h + (size_t)erow * 256 + cc * 32 + g8 * 8);
    // ---- prologue: stage 0 into Bst[0]
    {
        const _Float16* g = BfinV4 + (size_t)t * 16;
        f16x8 g0 = *(const f16x8*)g, g1 = *(const f16x8*)(g + 8);
        *(f16x8*)&Bst[0][t * 16] = g0;
        *(f16x8*)&Bst[0][t * 16 + 8] = g1;
    }
    __syncthreads();
    f32x4 acc[3][2];
#pragma unroll
    for (int l = 0; l < 3; ++l)
#pragma unroll
        for (int nt = 0; nt < 2; ++nt) acc[l][nt] = (f32x4){0.f, 0.f, 0.f, 0.f};
    int cur = 0;
#pragma unroll
    for (int l = 0; l < 3; ++l) {
#pragma unroll 1
        for (int ke = 0; ke < 32; ++ke) {
            int s = l * 32 + ke;
            f16x8 g0, g1;
            if (s < 95) {  // issue next-stage loads early
                const _Float16* g = BfinV4 + (size_t)(s + 1) * 8192 + t * 16;
                g0 = *(const f16x8*)g;
                g1 = *(const f16x8*)(g + 8);
            }
            _Float16 sh = s_S[(wave * 16 + r15) * SST + l * 32 + ke];
            f16x8 sb = {sh, sh, sh, sh, sh, sh, sh, sh};
#pragma unroll
            for (int nt = 0; nt < 2; ++nt) {
#pragma unroll
                for (int cc = 0; cc < 8; ++cc) {
                    f16x8 b = *(const f16x8*)&Bst[cur][(nt * 8 + cc) * 512 + lane * 8];
                    f16x8 ap = a2[cc] * sb;  // fold S into A
                    acc[l][nt] = __builtin_amdgcn_mfma_f32_16x16x32_f16(ap, b, acc[l][nt], 0, 0, 0);
                }
            }
            __syncthreads();             // all reads of Bst[cur] done
            if (s < 95) {
                *(f16x8*)&Bst[cur ^ 1][t * 16] = g0;
                *(f16x8*)&Bst[cur ^ 1][t * 16 + 8] = g1;
            }
            __syncthreads();             // stage s+1 visible
            cur ^= 1;
        }
    }
    // ---- apply w0, write scal f16 into s_S overlay (s_S dead after stage 95)
#pragma unroll
    for (int l = 0; l < 3; ++l) {
#pragma unroll
        for (int nt = 0; nt < 2; ++nt) {
#pragma unroll
            for (int i2 = 0; i2 < 4; ++i2) {
                int row = g8 * 4 + i2;                 // D row (16x16 layout)
                int jo = nt * 16 + r15;                // output col within l
                float w0 = (float)w0h[(size_t)(e0 + wave * 16 + row) * 96 + jo * 3 + l];
                s_S[(wave * 16 + row) * SST + l * 32 + jo] =
                    (_Float16)(acc[l][nt][i2] * w0);
            }
        }
    }
    __syncthreads();
    // ---- readout: waves = 4 mh2 (32 rows) x 2 w2 (nt-halves); A from global/scal
    int mh2 = wave >> 1, w2 = wave & 1;
    f32x4 racc[8][2];
#pragma unroll
    for (int i = 0; i < 8; ++i)
#pragma unroll
        for (int mt2 = 0; mt2 < 2; ++mt2) racc[i][mt2] = (f32x4){0.f, 0.f, 0.f, 0.f};
#pragma unroll
    for (int ks = 0; ks < 11; ++ks) {
        f16x8 af0, af1;
        if (ks < 8) {
            af0 = *(const f16x8*)(lat1h + (size_t)(e0 + mh2 * 32 + r15) * 256 + ks * 32 + g8 * 8);
            af1 = *(const f16x8*)(lat1h + (size_t)(e0 + mh2 * 32 + 16 + r15) * 256 + ks * 32 + g8 * 8);
        } else {
            af0 = *(const f16x8*)(s_S + (mh2 * 32 + r15) * SST + (ks - 8) * 32 + g8 * 8);
            af1 = *(const f16x8*)(s_S + (mh2 * 32 + 16 + r15) * SST + (ks - 8) * 32 + g8 * 8);
        }
#pragma unroll
        for (int i = 0; i < 8; ++i) {
            int nt = w2 + 2 * i;
            f16x8 b = *(const f16x8*)(Wro1T + ((size_t)(nt * 11 + ks) * 64 + lane) * 8);
            racc[i][0] = __builtin_amdgcn_mfma_f32_16x16x32_f16(af0, b, racc[i][0], 0, 0, 0);
            racc[i][1] = __builtin_amdgcn_mfma_f32_16x16x32_f16(af1, b, racc[i][1], 0, 0, 0);
        }
    }
    float v[2][4];
#pragma unroll
    for (int mt2 = 0; mt2 < 2; ++mt2)
#pragma unroll
        for (int i2 = 0; i2 < 4; ++i2) v[mt2][i2] = 0.f;
#pragma unroll
    for (int i = 0; i < 8; ++i) {
        int col = (w2 + 2 * i) * 16 + r15;
        float w2f = Wro2[col];
#pragma unroll
        for (int mt2 = 0; mt2 < 2; ++mt2)
#pragma unroll
            for (int i2 = 0; i2 < 4; ++i2) v[mt2][i2] += silu(racc[i][mt2][i2]) * w2f;
    }
#pragma unroll
    for (int off = 1; off < 16; off <<= 1)
#pragma unroll
        for (int mt2 = 0; mt2 < 2; ++mt2)
#pragma unroll
            for (int i2 = 0; i2 < 4; ++i2) v[mt2][i2] += __shfl_xor(v[mt2][i2], off);
    if (r15 == 0) {
#pragma unroll
        for (int mt2 = 0; mt2 < 2; ++mt2)
#pragma unroll
            for (int i2 = 0; i2 < 4; ++i2)
                s_ps[mh2 * 32 + mt2 * 16 + g8 * 4 + i2][w2] = v[mt2][i2];
    }
    __syncthreads();
    if (t < FEB) out[e0 + t] = s_ps[t][0] + s_ps[t][1];
}

// ----------------------------------------------------------------
extern "C" void kernel_launch(void* const* d_in, const int* in_sizes, int n_in,
                              void* d_out, int out_size, void* d_ws, size_t ws_size,
                              hipStream_t stream) {
    (void)in_sizes; (void)n_in; (void)out_size;
    const float* edge_attr = (const float*)d_in[0];
    const float* edge_len  = (const float*)d_in[1];
    const float* edge_inv  = (const float*)d_in[2];
    const float* node_inv  = (const float*)d_in[3];
    const float* W2a     = (const float*)d_in[4];
    const float* W2b     = (const float*)d_in[5];
    const float* Wl1a    = (const float*)d_in[6];
    const float* Wl1b    = (const float*)d_in[7];
    const float* Wenv0   = (const float*)d_in[8];
    const float* Wenv1   = (const float*)d_in[9];
    const float* Wenvlin = (const float*)d_in[10];
    const float* Wprod   = (const float*)d_in[11];
    const float* Wfeat   = (const float*)d_in[12];
    const float* Wfinlat = (const float*)d_in[13];
    const float* Wro1    = (const float*)d_in[14];
    const float* Wro2    = (const float*)d_in[15];
    const int* eidx      = (const int*)d_in[16];
    float* out = (float*)d_out;

    _Float16* p = (_Float16*)d_ws;
    _Float16* Bfin    = p; p += 786432;
    _Float16* BfinV4  = p; p += 786432;
    _Float16* W2aT    = p; p += 40960;
    _Float16* W2bT    = p; p += 65536;
    _Float16* Wenv0aT = p; p += 24576;
    _Float16* Wenv0bT = p; p += 24576;
    _Float16* Wenv1T  = p; p += 24576;
    _Float16* Wl1aT   = p; p += 90112;
    _Float16* Wl1bT   = p; p += 65536;
    _Float16* Wro1T   = p; p += 90112;
    float* env    = (float*)p;
    float* featN0 = env + (size_t)NNODES * 288;
    char* after = (char*)(featN0 + (size_t)NNODES * 288);
    size_t need_slow = (size_t)(after - (char*)d_ws);
    if (ws_size < need_slow) return;
    _Float16* lat1h = (_Float16*)after;                       // NE*256 f16
    _Float16* w0h   = lat1h + (size_t)NE * 256;               // NE*96 f16
    size_t need_fast = need_slow + (size_t)NE * (256 + 96) * sizeof(_Float16);
    bool fast = (ws_size >= need_fast);
    if (!fast) { lat1h = nullptr; w0h = nullptr; }

    const int ENV_N = NNODES * 288;
    k_packfin<<<3072, 256, 0, stream>>>(Wfinlat, Bfin);
    k_packfin4<<<3072, 256, 0, stream>>>(Wfinlat, BfinV4);
    k_packf<<<160, 256, 0, stream>>>(W2a, W2aT, 136, 5, 16, 256, 0);
    k_packf<<<256, 256, 0, stream>>>(W2b, W2bT, 256, 8, 16, 256, 0);
    k_packf<<<96, 256, 0, stream>>>(Wenv0, Wenv0aT, 256, 8, 6, 192, 0);
    k_packf<<<96, 256, 0, stream>>>(Wenv0, Wenv0bT, 256, 8, 6, 192, 96);
    k_packf<<<96, 256, 0, stream>>>(Wenv1, Wenv1T, 256, 8, 6, 96, 0);
    k_packf<<<352, 256, 0, stream>>>(Wl1a, Wl1aT, 352, 11, 16, 256, 0);
    k_packf<<<256, 256, 0, stream>>>(Wl1b, Wl1bT, 256, 8, 16, 256, 0);
    k_packf<<<352, 256, 0, stream>>>(Wro1, Wro1T, 352, 11, 16, 256, 0);

    k_zero<<<(ENV_N + 255) / 256, 256, 0, stream>>>(env, ENV_N);
    k1_lat_scatter0<<<NBLK, 256, 0, stream>>>(node_inv, edge_inv, edge_len, edge_attr,
                                              eidx, W2aT, W2bT, Wenv0bT, env);
    k_node<<<NNODES, 288, 0, stream>>>(env, node_inv, Wenvlin, Wprod, Wfeat, featN0);
    k_zero<<<(ENV_N + 255) / 256, 256, 0, stream>>>(env, ENV_N);
    k3_update_scatter1<<<NBLK, 256, 0, stream>>>(node_inv, edge_inv, edge_len, edge_attr,
                                                 eidx, W2aT, W2bT, Wl1aT, Wl1bT, Wenv1T,
                                                 Wenv0aT, featN0, env, lat1h, w0h);
    k_node<<<NNODES, 288, 0, stream>>>(env, node_inv, Wenvlin + 3072, Wprod + 6144,
                                       Wfeat + 3072, env);  // in-place: env1 -> featN1
    if (fast) {
        k5_fast<<<NE / FEB, 512, 0, stream>>>(edge_attr, eidx, lat1h, w0h, BfinV4, Wro1T,
                                              Wro2, env, out);
    } else {
        k5_final<<<NBLK, 256, 0, stream>>>(node_inv, edge_inv, edge_len, edge_attr, eidx,
                                           W2aT, W2bT, Wenv0aT, Wl1aT, Wl1bT, Bfin, Wro1T,
                                           Wro2, featN0, env, out);
    }
}